// Round 1
// baseline (562.927 us; speedup 1.0000x reference)
//
#include <hip/hip_runtime.h>
#include <math.h>

#define HEADS 16
#define HDIM  64
#define BATCH 4
#define SEQ   1024
#define ROWS  (BATCH*SEQ)    // 4096
#define EMB   1024
#define MN    32             // Chebyshev nodes

// ---------- fold: uq[e][n] = Wq[e, n*64:].w1 ; uk likewise with w2 ; cq[n]=bq.w1 ----------
__global__ __launch_bounds__(256) void fold_kernel(
    const float* __restrict__ Wq, const float* __restrict__ Wk,
    const float* __restrict__ bq, const float* __restrict__ attn_w,
    float* __restrict__ uq, float* __restrict__ uk, float* __restrict__ cq)
{
  int bid = blockIdx.x;
  if (bid < 128) {
    int idx = bid*256 + threadIdx.x;       // 0..32767
    bool isQ = idx < 16384;
    int li = isQ ? idx : idx - 16384;      // li = e*16 + n
    int e = li >> 4, n = li & 15;
    const float* W = isQ ? Wq : Wk;
    const float* w = isQ ? attn_w : attn_w + HDIM;
    const float* wp = &W[(size_t)e*EMB + n*HDIM];
    float s = 0.f;
    #pragma unroll 16
    for (int d = 0; d < HDIM; ++d) s = fmaf(wp[d], w[d], s);
    (isQ ? uq : uk)[li] = s;
  } else if (threadIdx.x < 16) {
    int n = threadIdx.x;
    float s = 0.f;
    for (int d = 0; d < HDIM; ++d) s = fmaf(bq[n*HDIM+d], attn_w[d], s);
    cq[n] = s;
  }
}

// ---------- sq = q @ uq + cq ; sk = k @ uk  (thin GEMM, one block per row) ----------
__global__ __launch_bounds__(256) void sqsk_kernel(
    const float* __restrict__ q, const float* __restrict__ k,
    const float* __restrict__ uq, const float* __restrict__ uk,
    const float* __restrict__ cq, float* __restrict__ sq, float* __restrict__ sk)
{
  __shared__ float rowbuf[EMB];
  __shared__ float part[16][17];
  int bid = blockIdx.x;
  bool isQ = bid < ROWS;
  int row = isQ ? bid : bid - ROWS;
  const float* X = isQ ? q : k;
  const float* U = isQ ? uq : uk;
  int tid = threadIdx.x;
  *reinterpret_cast<float4*>(&rowbuf[tid*4]) =
      *reinterpret_cast<const float4*>(&X[(size_t)row*EMB + tid*4]);
  __syncthreads();
  int n = tid & 15, ch = tid >> 4;
  float s = 0.f;
  #pragma unroll 8
  for (int e0 = 0; e0 < 64; ++e0) {
    int e = ch*64 + e0;
    s = fmaf(rowbuf[e], U[e*16 + n], s);
  }
  part[ch][n] = s;
  __syncthreads();
  if (tid < 16) {
    float t = isQ ? cq[tid] : 0.f;
    #pragma unroll
    for (int c = 0; c < 16; ++c) t += part[c][tid];
    (isQ ? sq : sk)[(size_t)row*16 + tid] = t;
  }
}

// ---------- per (b,n): min/max of sq -> 32 Chebyshev nodes ----------
__global__ __launch_bounds__(256) void nodes_kernel(const float* __restrict__ sq,
                                                    float* __restrict__ nodes)
{
  int bn = blockIdx.x;            // b*16+n
  int b = bn >> 4, n = bn & 15;
  int tid = threadIdx.x;
  float mn = 1e30f, mx = -1e30f;
  #pragma unroll
  for (int s = 0; s < 4; ++s) {
    float v = sq[((size_t)(b*SEQ + tid + s*256))*16 + n];
    mn = fminf(mn, v); mx = fmaxf(mx, v);
  }
  __shared__ float smn[256], smx[256];
  smn[tid] = mn; smx[tid] = mx;
  __syncthreads();
  for (int off = 128; off > 0; off >>= 1) {
    if (tid < off) { smn[tid] = fminf(smn[tid], smn[tid+off]);
                     smx[tid] = fmaxf(smx[tid], smx[tid+off]); }
    __syncthreads();
  }
  if (tid < MN) {
    float c = 0.5f*(smn[0] + smx[0]);
    float r = fmaxf(0.5f*(smx[0] - smn[0]), 1e-4f);
    nodes[bn*MN + tid] = c + r * cosf(tid * (3.14159265358979323f / (MN-1)));
  }
}

// ---------- fp32 SGEMM: C = A(MxK) @ B(KxN) [+bias], row-major, 128x128x16 ----------
__global__ __launch_bounds__(256) void sgemm128(
    const float* __restrict__ A, const float* __restrict__ Bm,
    const float* __restrict__ bias, float* __restrict__ C,
    int M, int N, int K, int hasBias)
{
  constexpr int BMt = 128, BNt = 128, BKt = 16, PAD = 4;
  __shared__ float As[BKt][BMt+PAD];
  __shared__ float Bs[BKt][BNt+PAD];
  const int tid = threadIdx.x;
  const int bm0 = blockIdx.y * BMt;
  const int bn0 = blockIdx.x * BNt;
  const int tm = tid >> 4;          // 0..15
  const int tn = tid & 15;          // 0..15
  const int m0 = tm * 8;
  const int nA = tn * 4;            // cols [nA, nA+3]
  const int nB = 64 + tn * 4;       // cols [nB, nB+3]
  float4 acc0[8], acc1[8];
  #pragma unroll
  for (int r = 0; r < 8; ++r) {
    acc0[r] = make_float4(0,0,0,0); acc1[r] = make_float4(0,0,0,0);
  }
  const int ar  = tid >> 2;         // 0..63
  const int ac4 = (tid & 3) * 4;    // k offset
  const int br  = tid >> 5;         // 0..7
  const int bc4 = (tid & 31) * 4;

  for (int k0 = 0; k0 < K; k0 += BKt) {
    __syncthreads();
    #pragma unroll
    for (int p = 0; p < 2; ++p) {
      float4 a = *reinterpret_cast<const float4*>(
          &A[(size_t)(bm0 + ar + p*64)*K + k0 + ac4]);
      As[ac4+0][ar + p*64] = a.x; As[ac4+1][ar + p*64] = a.y;
      As[ac4+2][ar + p*64] = a.z; As[ac4+3][ar + p*64] = a.w;
    }
    #pragma unroll
    for (int p = 0; p < 2; ++p) {
      float4 b = *reinterpret_cast<const float4*>(
          &Bm[(size_t)(k0 + br + p*8)*N + bn0 + bc4]);
      *reinterpret_cast<float4*>(&Bs[br + p*8][bc4]) = b;
    }
    __syncthreads();
    #pragma unroll
    for (int kk = 0; kk < BKt; ++kk) {
      float4 a0 = *reinterpret_cast<const float4*>(&As[kk][m0]);
      float4 a1 = *reinterpret_cast<const float4*>(&As[kk][m0+4]);
      float4 b0 = *reinterpret_cast<const float4*>(&Bs[kk][nA]);
      float4 b1 = *reinterpret_cast<const float4*>(&Bs[kk][nB]);
      float am[8] = {a0.x,a0.y,a0.z,a0.w,a1.x,a1.y,a1.z,a1.w};
      #pragma unroll
      for (int r = 0; r < 8; ++r) {
        acc0[r].x = fmaf(am[r], b0.x, acc0[r].x);
        acc0[r].y = fmaf(am[r], b0.y, acc0[r].y);
        acc0[r].z = fmaf(am[r], b0.z, acc0[r].z);
        acc0[r].w = fmaf(am[r], b0.w, acc0[r].w);
        acc1[r].x = fmaf(am[r], b1.x, acc1[r].x);
        acc1[r].y = fmaf(am[r], b1.y, acc1[r].y);
        acc1[r].z = fmaf(am[r], b1.z, acc1[r].z);
        acc1[r].w = fmaf(am[r], b1.w, acc1[r].w);
      }
    }
  }
  float4 bv0 = make_float4(0,0,0,0), bv1 = make_float4(0,0,0,0);
  if (hasBias) {
    bv0 = *reinterpret_cast<const float4*>(&bias[bn0 + nA]);
    bv1 = *reinterpret_cast<const float4*>(&bias[bn0 + nB]);
  }
  #pragma unroll
  for (int r = 0; r < 8; ++r) {
    int row = bm0 + m0 + r;
    float4 v0 = acc0[r], v1 = acc1[r];
    v0.x += bv0.x; v0.y += bv0.y; v0.z += bv0.z; v0.w += bv0.w;
    v1.x += bv1.x; v1.y += bv1.y; v1.z += bv1.z; v1.w += bv1.w;
    *reinterpret_cast<float4*>(&C[(size_t)row*N + bn0 + nA]) = v0;
    *reinterpret_cast<float4*>(&C[(size_t)row*N + bn0 + nB]) = v1;
  }
}

// ---------- G[bn][m][d] = sum_j exp(tanh(s_m + sk_j)) * [vh_j ; 1] ----------
__global__ __launch_bounds__(256) void gaccum_kernel(
    const float* __restrict__ sk, const float* __restrict__ vh,
    const float* __restrict__ nodes, float* __restrict__ G)
{
  int bn = blockIdx.y;              // b*16+n
  int b = bn >> 4, n = bn & 15;
  int j0 = blockIdx.x * 256;
  int tid = threadIdx.x;
  int m = tid >> 3, g = tid & 7;
  __shared__ float sksh[256];
  sksh[tid] = sk[((size_t)(b*SEQ + j0 + tid))*16 + n];
  __syncthreads();
  float sm = nodes[bn*MN + m];
  float acc[8] = {0,0,0,0,0,0,0,0};
  float accw = 0.f;
  for (int t = 0; t < 256; ++t) {
    float s = sm + sksh[t];
    float w = expf(tanhf(s));
    accw += w;
    const float* vp = &vh[((size_t)(b*SEQ + j0 + t))*EMB + n*HDIM + g];
    #pragma unroll
    for (int u = 0; u < 8; ++u) acc[u] = fmaf(w, vp[u*8], acc[u]);
  }
  float* Gp = &G[((size_t)bn*MN + m)*65];
  #pragma unroll
  for (int u = 0; u < 8; ++u) atomicAdd(&Gp[g + 8*u], acc[u]);
  if (g == 0) atomicAdd(&Gp[64], accw);
}

// ---------- barycentric interpolation at s=sq -> attn_out ----------
__global__ __launch_bounds__(256) void interp_kernel(
    const float* __restrict__ sq, const float* __restrict__ nodes,
    const float* __restrict__ G, float* __restrict__ attn)
{
  int wid  = (blockIdx.x*256 + threadIdx.x) >> 6;  // task = row*16+n
  int lane = threadIdx.x & 63;
  int n = wid & 15;
  int row = wid >> 4;               // b*SEQ+i
  int b = row >> 10;
  int bn = b*16 + n;
  float s = sq[wid];
  const float* Gp = &G[(size_t)bn*MN*65];
  const float* np = &nodes[bn*MN];
  float num = 0.f, den = 0.f;
  int ex = -1;
  #pragma unroll 8
  for (int m = 0; m < MN; ++m) {
    float smv = np[m];
    float diff = s - smv;
    float wb = ((m == 0) | (m == MN-1)) ? 0.5f : 1.0f;
    wb = (m & 1) ? -wb : wb;
    if (diff == 0.f) ex = m;
    float lam = wb / diff;
    num = fmaf(lam, Gp[m*65 + lane], num);
    den = fmaf(lam, Gp[m*65 + 64], den);
  }
  float outv = (ex >= 0) ? (Gp[ex*65 + lane] / Gp[ex*65 + 64]) : (num / den);
  attn[(size_t)row*EMB + n*HDIM + lane] = outv;
}

// ---------- row LayerNorm in-place on d_out ----------
__global__ __launch_bounds__(256) void ln_kernel(
    float* __restrict__ out, const float* __restrict__ gamma,
    const float* __restrict__ beta)
{
  int row = blockIdx.x, tid = threadIdx.x;
  float4 x = *reinterpret_cast<float4*>(&out[(size_t)row*EMB + tid*4]);
  float sum = x.x + x.y + x.z + x.w;
  float ssq = x.x*x.x + x.y*x.y + x.z*x.z + x.w*x.w;
  #pragma unroll
  for (int off = 32; off > 0; off >>= 1) {
    sum += __shfl_down(sum, off);
    ssq += __shfl_down(ssq, off);
  }
  __shared__ float red[8];
  int wave = tid >> 6, lane = tid & 63;
  if (lane == 0) { red[wave] = sum; red[4+wave] = ssq; }
  __syncthreads();
  if (tid == 0) {
    float a = red[0]+red[1]+red[2]+red[3];
    float q = red[4]+red[5]+red[6]+red[7];
    float mean = a * (1.f/EMB);
    float var  = q * (1.f/EMB) - mean*mean;
    red[0] = mean;
    red[1] = 1.0f / sqrtf(var + 1e-6f);
  }
  __syncthreads();
  float mean = red[0], inv = red[1];
  float4 gv = *reinterpret_cast<const float4*>(&gamma[tid*4]);
  float4 bv = *reinterpret_cast<const float4*>(&beta[tid*4]);
  x.x = (x.x - mean)*inv*gv.x + bv.x;
  x.y = (x.y - mean)*inv*gv.y + bv.y;
  x.z = (x.z - mean)*inv*gv.z + bv.z;
  x.w = (x.w - mean)*inv*gv.w + bv.w;
  *reinterpret_cast<float4*>(&out[(size_t)row*EMB + tid*4]) = x;
}

extern "C" void kernel_launch(void* const* d_in, const int* in_sizes, int n_in,
                              void* d_out, int out_size, void* d_ws, size_t ws_size,
                              hipStream_t stream)
{
  const float* k   = (const float*)d_in[0];
  const float* q   = (const float*)d_in[1];
  const float* v   = (const float*)d_in[2];
  const float* Wq  = (const float*)d_in[3];
  const float* bq  = (const float*)d_in[4];
  const float* Wk  = (const float*)d_in[5];
  const float* Wv  = (const float*)d_in[6];
  const float* Wp  = (const float*)d_in[7];
  const float* bp  = (const float*)d_in[8];
  const float* aw  = (const float*)d_in[9];
  const float* gamma = (const float*)d_in[10];
  const float* beta  = (const float*)d_in[11];
  float* out = (float*)d_out;

  float* ws   = (float*)d_ws;
  float* uq   = ws;                       // 16384
  float* uk   = uq + 16384;               // 16384
  float* cq   = uk + 16384;               // 16
  float* sq   = cq + 16;                  // 65536
  float* sk   = sq + 65536;               // 65536
  float* nodes= sk + 65536;               // 64*32 = 2048
  float* G    = nodes + 2048;             // 64*32*65 = 133120
  float* vh   = G + 133120;               // 4194304
  float* attn = vh + 4194304;             // 4194304

  // 1. fold weights
  fold_kernel<<<129, 256, 0, stream>>>(Wq, Wk, bq, aw, uq, uk, cq);
  // 2. sq / sk
  sqsk_kernel<<<2*ROWS, 256, 0, stream>>>(q, k, uq, uk, cq, sq, sk);
  // 3. Chebyshev nodes per (b,n)
  nodes_kernel<<<64, 256, 0, stream>>>(sq, nodes);
  // 4. zero G
  hipMemsetAsync(G, 0, (size_t)64*MN*65*sizeof(float), stream);
  // 5. vh = v @ Wv
  {
    dim3 grid(EMB/128, ROWS/128);
    sgemm128<<<grid, 256, 0, stream>>>(v, Wv, nullptr, vh, ROWS, EMB, EMB, 0);
  }
  // 6. accumulate G
  {
    dim3 grid(4, 64);
    gaccum_kernel<<<grid, 256, 0, stream>>>(sk, vh, nodes, G);
  }
  // 7. interpolate -> attn_out
  interp_kernel<<<(ROWS*HEADS)/4, 256, 0, stream>>>(sq, nodes, G, attn);
  // 8. out = attn_out @ Wp + bp
  {
    dim3 grid(EMB/128, ROWS/128);
    sgemm128<<<grid, 256, 0, stream>>>(attn, Wp, bp, out, ROWS, EMB, EMB, 1);
  }
  // 9. LayerNorm in-place
  ln_kernel<<<ROWS, 256, 0, stream>>>(out, gamma, beta);
}

// Round 2
// 344.829 us; speedup vs baseline: 1.6325x; 1.6325x over previous
//
#include <hip/hip_runtime.h>
#include <math.h>

#define HEADS 16
#define HDIM  64
#define SEQ   1024
#define ROWS  4096
#define EMB   1024
#define MN    32

typedef _Float16 f16;
typedef __attribute__((ext_vector_type(4))) _Float16 f16x4;
typedef __attribute__((ext_vector_type(8))) _Float16 f16x8;
typedef __attribute__((ext_vector_type(4))) float f32x4;

// ---------- fold: uq[e][n] = Wq[e, n*64:].w1 ; uk likewise with w2 ; cq[n]=bq.w1 ----------
__global__ __launch_bounds__(256) void fold_kernel(
    const float* __restrict__ Wq, const float* __restrict__ Wk,
    const float* __restrict__ bq, const float* __restrict__ attn_w,
    float* __restrict__ uq, float* __restrict__ uk, float* __restrict__ cq)
{
  int bid = blockIdx.x;
  if (bid < 128) {
    int idx = bid*256 + threadIdx.x;       // 0..32767
    bool isQ = idx < 16384;
    int li = isQ ? idx : idx - 16384;      // li = e*16 + n
    int e = li >> 4, n = li & 15;
    const float* W = isQ ? Wq : Wk;
    const float* w = isQ ? attn_w : attn_w + HDIM;
    const float* wp = &W[(size_t)e*EMB + n*HDIM];
    float s = 0.f;
    #pragma unroll 16
    for (int d = 0; d < HDIM; ++d) s = fmaf(wp[d], w[d], s);
    (isQ ? uq : uk)[li] = s;
  } else if (threadIdx.x < 16) {
    int n = threadIdx.x;
    float s = 0.f;
    for (int d = 0; d < HDIM; ++d) s = fmaf(bq[n*HDIM+d], attn_w[d], s);
    cq[n] = s;
  }
}

// ---------- sq = q @ uq + cq ; sk = k @ uk  (thin GEMM, one block per row) ----------
__global__ __launch_bounds__(256) void sqsk_kernel(
    const float* __restrict__ q, const float* __restrict__ k,
    const float* __restrict__ uq, const float* __restrict__ uk,
    const float* __restrict__ cq, float* __restrict__ sq, float* __restrict__ sk)
{
  __shared__ float rowbuf[EMB];
  __shared__ float part[16][17];
  int bid = blockIdx.x;
  bool isQ = bid < ROWS;
  int row = isQ ? bid : bid - ROWS;
  const float* X = isQ ? q : k;
  const float* U = isQ ? uq : uk;
  int tid = threadIdx.x;
  *reinterpret_cast<float4*>(&rowbuf[tid*4]) =
      *reinterpret_cast<const float4*>(&X[(size_t)row*EMB + tid*4]);
  __syncthreads();
  int n = tid & 15, ch = tid >> 4;
  float s = 0.f;
  #pragma unroll 8
  for (int e0 = 0; e0 < 64; ++e0) {
    int e = ch*64 + e0;
    s = fmaf(rowbuf[e], U[e*16 + n], s);
  }
  part[ch][n] = s;
  __syncthreads();
  if (tid < 16) {
    float t = isQ ? cq[tid] : 0.f;
    #pragma unroll
    for (int c = 0; c < 16; ++c) t += part[c][tid];
    (isQ ? sq : sk)[(size_t)row*16 + tid] = t;
  }
}

// ---------- per (b,n): min/max of sq -> 32 Chebyshev nodes ----------
__global__ __launch_bounds__(256) void nodes_kernel(const float* __restrict__ sq,
                                                    float* __restrict__ nodes)
{
  int bn = blockIdx.x;            // b*16+n
  int b = bn >> 4, n = bn & 15;
  int tid = threadIdx.x;
  float mn = 1e30f, mx = -1e30f;
  #pragma unroll
  for (int s = 0; s < 4; ++s) {
    float v = sq[((size_t)(b*SEQ + tid + s*256))*16 + n];
    mn = fminf(mn, v); mx = fmaxf(mx, v);
  }
  __shared__ float smn[256], smx[256];
  smn[tid] = mn; smx[tid] = mx;
  __syncthreads();
  for (int off = 128; off > 0; off >>= 1) {
    if (tid < off) { smn[tid] = fminf(smn[tid], smn[tid+off]);
                     smx[tid] = fmaxf(smx[tid], smx[tid+off]); }
    __syncthreads();
  }
  if (tid < MN) {
    float c = 0.5f*(smn[0] + smx[0]);
    float r = fmaxf(0.5f*(smx[0] - smn[0]), 1e-4f);
    nodes[bn*MN + tid] = c + r * cosf(tid * (3.14159265358979323f / (MN-1)));
  }
}

// ---------- weight prep: transpose + fp16 split  WT[n][k] = W[k][n] ----------
__global__ __launch_bounds__(256) void wprep_kernel(
    const float* __restrict__ Wv, const float* __restrict__ Wp,
    f16* __restrict__ WvTh, f16* __restrict__ WvTl,
    f16* __restrict__ WpTh, f16* __restrict__ WpTl)
{
  __shared__ float tile[64][65];
  const float* W = blockIdx.z ? Wp : Wv;
  f16* Th = blockIdx.z ? WpTh : WvTh;
  f16* Tl = blockIdx.z ? WpTl : WvTl;
  int k0 = blockIdx.y * 64, n0 = blockIdx.x * 64;
  int t = threadIdx.x, rr = t >> 4, c4 = (t & 15) * 4;
  #pragma unroll
  for (int i = 0; i < 4; ++i) {
    int row = rr + i * 16;
    float4 w = *reinterpret_cast<const float4*>(&W[(size_t)(k0 + row) * EMB + n0 + c4]);
    tile[row][c4] = w.x; tile[row][c4+1] = w.y;
    tile[row][c4+2] = w.z; tile[row][c4+3] = w.w;
  }
  __syncthreads();
  #pragma unroll
  for (int i = 0; i < 4; ++i) {
    int nn = rr + i * 16;
    f16x4 hh, ll;
    #pragma unroll
    for (int jj = 0; jj < 4; ++jj) {
      float x = tile[c4 + jj][nn];
      f16 h = (f16)x;
      hh[jj] = h;
      ll[jj] = (f16)(x - (float)h);
    }
    *reinterpret_cast<f16x4*>(&Th[(size_t)(n0 + nn) * EMB + k0 + c4]) = hh;
    *reinterpret_cast<f16x4*>(&Tl[(size_t)(n0 + nn) * EMB + k0 + c4]) = ll;
  }
}

// ---------- elementwise fp16 split of v ----------
__global__ __launch_bounds__(256) void split_kernel(
    const float* __restrict__ in, f16* __restrict__ h, f16* __restrict__ l)
{
  size_t i = ((size_t)blockIdx.x * 256 + threadIdx.x) * 4;
  float4 x = *reinterpret_cast<const float4*>(&in[i]);
  float xs[4] = {x.x, x.y, x.z, x.w};
  f16x4 hh, ll;
  #pragma unroll
  for (int jj = 0; jj < 4; ++jj) {
    f16 hv = (f16)xs[jj];
    hh[jj] = hv;
    ll[jj] = (f16)(xs[jj] - (float)hv);
  }
  *reinterpret_cast<f16x4*>(&h[i]) = hh;
  *reinterpret_cast<f16x4*>(&l[i]) = ll;
}

// ---------- fp16 split-3 MFMA GEMM: C = A @ B^T' (B given transposed [N][K]) ----------
// tile 128x64, BK=64, 4 waves (2x2), global_load_lds staging, XOR-swizzled LDS
#define GBM 128
#define GBN 64
#define GBK 64

__global__ __launch_bounds__(256) void gemm_split(
    const f16* __restrict__ Ah, const f16* __restrict__ Al,
    const f16* __restrict__ Bh, const f16* __restrict__ Bl,
    const float* __restrict__ bias, float* __restrict__ C,
    int M, int N, int K, int hasBias)
{
  __shared__ __align__(16) char lds[49152];   // Ah 16K | Al 16K | Bh 8K | Bl 8K
  const int tid = threadIdx.x;
  const int wid = tid >> 6, lane = tid & 63;
  const int brow = blockIdx.y * GBM;
  const int bcol = blockIdx.x * GBN;
  const int wm = wid >> 1, wn = wid & 1;
  const int asel = lane >> 4;
  const int l15 = lane & 15;

  f32x4 acc[4][2];
  #pragma unroll
  for (int i = 0; i < 4; ++i)
    #pragma unroll
    for (int jx = 0; jx < 2; ++jx)
      acc[i][jx] = (f32x4){0.f, 0.f, 0.f, 0.f};

  const int NT = K / GBK;
  for (int t = 0; t < NT; ++t) {
    const int k0 = t * GBK;
    __syncthreads();
    // stage: 12 rounds x 256 lanes x 16B. LDS dest linear; global source
    // pre-swizzled so that reads below (kc ^ (row&7)) see the right data.
    #pragma unroll
    for (int r = 0; r < 12; ++r) {
      const char* src;
      if (r < 8) {
        int ci = ((r & 3) << 8) + tid;        // chunk in A array
        int row = ci >> 3, kc = ci & 7;
        int kcg = kc ^ (row & 7);
        const f16* base = (r < 4) ? Ah : Al;
        src = (const char*)(base + (size_t)(brow + row) * K + k0 + kcg * 8);
      } else {
        int ci = ((r & 1) << 8) + tid;        // chunk in B array
        int col = ci >> 3, kc = ci & 7;
        int kcg = kc ^ (col & 7);
        const f16* base = (r < 10) ? Bh : Bl;
        src = (const char*)(base + (size_t)(bcol + col) * K + k0 + kcg * 8);
      }
      char* dst = lds + (r * 256 + wid * 64) * 16;
      __builtin_amdgcn_global_load_lds(
          (const __attribute__((address_space(1))) unsigned int*)src,
          (__attribute__((address_space(3))) unsigned int*)dst, 16, 0, 0);
    }
    __syncthreads();   // compiler drains vmcnt(0) here -> tile ready
    #pragma unroll
    for (int kk = 0; kk < 2; ++kk) {
      f16x8 afh[4], afl[4], bfh[2], bfl[2];
      #pragma unroll
      for (int mf = 0; mf < 4; ++mf) {
        int row = wm * 64 + mf * 16 + l15;
        int kcx = (kk * 4 + asel) ^ (row & 7);
        int off = row * 128 + kcx * 16;
        afh[mf] = *reinterpret_cast<const f16x8*>(lds + off);
        afl[mf] = *reinterpret_cast<const f16x8*>(lds + 16384 + off);
      }
      #pragma unroll
      for (int nf = 0; nf < 2; ++nf) {
        int col = wn * 32 + nf * 16 + l15;
        int kcx = (kk * 4 + asel) ^ (col & 7);
        int off = col * 128 + kcx * 16;
        bfh[nf] = *reinterpret_cast<const f16x8*>(lds + 32768 + off);
        bfl[nf] = *reinterpret_cast<const f16x8*>(lds + 40960 + off);
      }
      #pragma unroll
      for (int mf = 0; mf < 4; ++mf)
        #pragma unroll
        for (int nf = 0; nf < 2; ++nf) {
          acc[mf][nf] = __builtin_amdgcn_mfma_f32_16x16x32_f16(afh[mf], bfh[nf], acc[mf][nf], 0, 0, 0);
          acc[mf][nf] = __builtin_amdgcn_mfma_f32_16x16x32_f16(afh[mf], bfl[nf], acc[mf][nf], 0, 0, 0);
          acc[mf][nf] = __builtin_amdgcn_mfma_f32_16x16x32_f16(afl[mf], bfh[nf], acc[mf][nf], 0, 0, 0);
        }
    }
  }
  // epilogue: C/D layout col=lane&15, row=(lane>>4)*4+j
  const int crow0 = brow + wm * 64 + asel * 4;
  const int ccol0 = bcol + wn * 32 + l15;
  #pragma unroll
  for (int nf = 0; nf < 2; ++nf) {
    float bv = hasBias ? bias[ccol0 + nf * 16] : 0.f;
    #pragma unroll
    for (int mf = 0; mf < 4; ++mf)
      #pragma unroll
      for (int jx = 0; jx < 4; ++jx)
        C[(size_t)(crow0 + mf * 16 + jx) * N + ccol0 + nf * 16] = acc[mf][nf][jx] + bv;
  }
}

// ---------- G accumulation, LDS-staged: G[bn][m][d] += sum_j w(m,j) * [vh;1] ----------
__global__ __launch_bounds__(256) void gaccum2_kernel(
    const float* __restrict__ sk, const float* __restrict__ vh,
    const float* __restrict__ nodes, float* __restrict__ G)
{
  __shared__ float sksh[128];
  __shared__ float nsh[32];
  __shared__ float wsh[32 * 132];               // padded stride vs 128
  __shared__ __align__(16) float vtile[128 * 64];
  const int bn = blockIdx.y, b = bn >> 4, n = bn & 15;
  const int j0 = blockIdx.x * 128;
  const int tid = threadIdx.x;
  if (tid < 128) sksh[tid] = sk[(size_t)(b * SEQ + j0 + tid) * 16 + n];
  else if (tid < 160) nsh[tid - 128] = nodes[bn * MN + (tid - 128)];
  #pragma unroll
  for (int i = 0; i < 8; ++i) {
    int fi = tid + i * 256;
    int row = fi >> 4, c4 = (fi & 15) * 4;
    *reinterpret_cast<float4*>(&vtile[row * 64 + c4]) =
        *reinterpret_cast<const float4*>(&vh[(size_t)(b * SEQ + j0 + row) * EMB + n * HDIM + c4]);
  }
  __syncthreads();
  {
    int mw = tid >> 3;
    int jb = (tid & 7) * 16;
    float nm = nsh[mw];
    #pragma unroll
    for (int i = 0; i < 16; ++i) {
      int j = jb + i;
      float s = nm + sksh[j];
      float e2 = __expf(2.f * s);
      float th = 1.f - 2.f / (e2 + 1.f);        // tanh(s), inf-safe
      wsh[mw * 132 + j] = __expf(th);
    }
  }
  __syncthreads();
  const int m = tid >> 3, g = tid & 7;
  float4 a0 = make_float4(0,0,0,0), a1 = make_float4(0,0,0,0);
  float accw = 0.f;
  const float* wrow = &wsh[m * 132];
  #pragma unroll 4
  for (int j = 0; j < 128; ++j) {
    float w = wrow[j];
    float4 va = *reinterpret_cast<const float4*>(&vtile[j * 64 + g * 8]);
    float4 vb = *reinterpret_cast<const float4*>(&vtile[j * 64 + g * 8 + 4]);
    a0.x = fmaf(w, va.x, a0.x); a0.y = fmaf(w, va.y, a0.y);
    a0.z = fmaf(w, va.z, a0.z); a0.w = fmaf(w, va.w, a0.w);
    a1.x = fmaf(w, vb.x, a1.x); a1.y = fmaf(w, vb.y, a1.y);
    a1.z = fmaf(w, vb.z, a1.z); a1.w = fmaf(w, vb.w, a1.w);
    accw += w;
  }
  float* Gp = &G[((size_t)bn * MN + m) * 65];
  atomicAdd(&Gp[g*8+0], a0.x); atomicAdd(&Gp[g*8+1], a0.y);
  atomicAdd(&Gp[g*8+2], a0.z); atomicAdd(&Gp[g*8+3], a0.w);
  atomicAdd(&Gp[g*8+4], a1.x); atomicAdd(&Gp[g*8+5], a1.y);
  atomicAdd(&Gp[g*8+6], a1.z); atomicAdd(&Gp[g*8+7], a1.w);
  if (g == 0) atomicAdd(&Gp[64], accw);
}

// ---------- barycentric interpolation at s=sq -> attn_out (fp16 split output) ----------
__global__ __launch_bounds__(256) void interp_kernel(
    const float* __restrict__ sq, const float* __restrict__ nodes,
    const float* __restrict__ G, f16* __restrict__ ah, f16* __restrict__ al)
{
  int wid  = (blockIdx.x*256 + threadIdx.x) >> 6;  // task = row*16+n
  int lane = threadIdx.x & 63;
  int n = wid & 15;
  int row = wid >> 4;               // b*SEQ+i
  int b = row >> 10;
  int bn = b*16 + n;
  float s = sq[wid];
  const float* Gp = &G[(size_t)bn*MN*65];
  const float* np = &nodes[bn*MN];
  float num = 0.f, den = 0.f;
  int ex = -1;
  #pragma unroll 8
  for (int m = 0; m < MN; ++m) {
    float smv = np[m];
    float diff = s - smv;
    float wb = ((m == 0) | (m == MN-1)) ? 0.5f : 1.0f;
    wb = (m & 1) ? -wb : wb;
    if (diff == 0.f) ex = m;
    float lam = wb / diff;
    num = fmaf(lam, Gp[m*65 + lane], num);
    den = fmaf(lam, Gp[m*65 + 64], den);
  }
  float outv = (ex >= 0) ? (Gp[ex*65 + lane] / Gp[ex*65 + 64]) : (num / den);
  f16 hv = (f16)outv;
  f16 lv = (f16)(outv - (float)hv);
  size_t oidx = (size_t)row * EMB + n * HDIM + lane;
  ah[oidx] = hv;
  al[oidx] = lv;
}

// ---------- row LayerNorm in-place on d_out ----------
__global__ __launch_bounds__(256) void ln_kernel(
    float* __restrict__ out, const float* __restrict__ gamma,
    const float* __restrict__ beta)
{
  int row = blockIdx.x, tid = threadIdx.x;
  float4 x = *reinterpret_cast<float4*>(&out[(size_t)row*EMB + tid*4]);
  float sum = x.x + x.y + x.z + x.w;
  float ssq = x.x*x.x + x.y*x.y + x.z*x.z + x.w*x.w;
  #pragma unroll
  for (int off = 32; off > 0; off >>= 1) {
    sum += __shfl_down(sum, off);
    ssq += __shfl_down(ssq, off);
  }
  __shared__ float red[8];
  int wave = tid >> 6, lane = tid & 63;
  if (lane == 0) { red[wave] = sum; red[4+wave] = ssq; }
  __syncthreads();
  if (tid == 0) {
    float a = red[0]+red[1]+red[2]+red[3];
    float qq = red[4]+red[5]+red[6]+red[7];
    float mean = a * (1.f/EMB);
    float var  = qq * (1.f/EMB) - mean*mean;
    red[0] = mean;
    red[1] = 1.0f / sqrtf(var + 1e-6f);
  }
  __syncthreads();
  float mean = red[0], inv = red[1];
  float4 gv = *reinterpret_cast<const float4*>(&gamma[tid*4]);
  float4 bv = *reinterpret_cast<const float4*>(&beta[tid*4]);
  x.x = (x.x - mean)*inv*gv.x + bv.x;
  x.y = (x.y - mean)*inv*gv.y + bv.y;
  x.z = (x.z - mean)*inv*gv.z + bv.z;
  x.w = (x.w - mean)*inv*gv.w + bv.w;
  *reinterpret_cast<float4*>(&out[(size_t)row*EMB + tid*4]) = x;
}

extern "C" void kernel_launch(void* const* d_in, const int* in_sizes, int n_in,
                              void* d_out, int out_size, void* d_ws, size_t ws_size,
                              hipStream_t stream)
{
  const float* k   = (const float*)d_in[0];
  const float* q   = (const float*)d_in[1];
  const float* v   = (const float*)d_in[2];
  const float* Wq  = (const float*)d_in[3];
  const float* bq  = (const float*)d_in[4];
  const float* Wk  = (const float*)d_in[5];
  const float* Wv  = (const float*)d_in[6];
  const float* Wp  = (const float*)d_in[7];
  const float* bp  = (const float*)d_in[8];
  const float* aw  = (const float*)d_in[9];
  const float* gamma = (const float*)d_in[10];
  const float* beta  = (const float*)d_in[11];
  float* out = (float*)d_out;

  float* ws   = (float*)d_ws;
  float* uq   = ws;                        // 16384
  float* uk   = uq + 16384;                // 16384
  float* cq   = uk + 16384;                // 16
  float* sq   = cq + 16;                   // 65536
  float* sk   = sq + 65536;                // 65536
  float* nodes= sk + 65536;                // 2048
  float* G    = nodes + 2048;              // 64*32*65 = 133120
  float* vh   = G + 133120;                // 4194304 f32
  f16* vsh    = (f16*)(vh + 4194304);      // 4194304 f16
  f16* vsl    = vsh + 4194304;             // 4194304 f16
  f16* WvTh   = vsl + 4194304;             // 1048576 f16
  f16* WvTl   = WvTh + 1048576;
  f16* WpTh   = WvTl + 1048576;
  f16* WpTl   = WpTh + 1048576;
  f16* ath    = vsh;                       // alias: reused after gemm1 consumed v splits
  f16* atl    = vsl;

  // 1. fold attention weights into uq/uk/cq
  fold_kernel<<<129, 256, 0, stream>>>(Wq, Wk, bq, aw, uq, uk, cq);
  // 2. sq / sk thin GEMMs
  sqsk_kernel<<<2*ROWS, 256, 0, stream>>>(q, k, uq, uk, cq, sq, sk);
  // 3. Chebyshev nodes per (b,n)
  nodes_kernel<<<64, 256, 0, stream>>>(sq, nodes);
  // 4. zero G
  hipMemsetAsync(G, 0, (size_t)64*MN*65*sizeof(float), stream);
  // 5. weight transpose+split, v split
  wprep_kernel<<<dim3(16,16,2), 256, 0, stream>>>(Wv, Wp, WvTh, WvTl, WpTh, WpTl);
  split_kernel<<<4096, 256, 0, stream>>>(v, vsh, vsl);
  // 6. vh = v @ Wv   (fp16 split-3 MFMA)
  gemm_split<<<dim3(16,32), 256, 0, stream>>>(vsh, vsl, WvTh, WvTl, nullptr, vh,
                                              ROWS, EMB, EMB, 0);
  // 7. accumulate G
  gaccum2_kernel<<<dim3(8,64), 256, 0, stream>>>(sk, vh, nodes, G);
  // 8. interpolate -> attn (fp16 split, aliases v split space)
  interp_kernel<<<(ROWS*HEADS)/4, 256, 0, stream>>>(sq, nodes, G, ath, atl);
  // 9. out = attn @ Wp + bp   (fp16 split-3 MFMA)
  gemm_split<<<dim3(16,32), 256, 0, stream>>>(ath, atl, WpTh, WpTl, bp, out,
                                              ROWS, EMB, EMB, 1);
  // 10. LayerNorm in-place
  ln_kernel<<<ROWS, 256, 0, stream>>>(out, gamma, beta);
}

// Round 3
// 283.053 us; speedup vs baseline: 1.9888x; 1.2182x over previous
//
#include <hip/hip_runtime.h>
#include <math.h>

#define HEADS 16
#define HDIM  64
#define SEQ   1024
#define ROWS  4096
#define EMB   1024
#define MN    32

typedef _Float16 f16;
typedef __attribute__((ext_vector_type(4))) _Float16 f16x4;
typedef __attribute__((ext_vector_type(8))) _Float16 f16x8;
typedef __attribute__((ext_vector_type(4))) float f32x4;

// ---------- fold: uq[e][n] = Wq[e, n*64:].w1 ; uk likewise with w2 ; cq[n]=bq.w1 ----------
__global__ __launch_bounds__(256) void fold_kernel(
    const float* __restrict__ Wq, const float* __restrict__ Wk,
    const float* __restrict__ bq, const float* __restrict__ attn_w,
    float* __restrict__ uq, float* __restrict__ uk, float* __restrict__ cq)
{
  int bid = blockIdx.x;
  if (bid < 128) {
    int idx = bid*256 + threadIdx.x;       // 0..32767
    bool isQ = idx < 16384;
    int li = isQ ? idx : idx - 16384;      // li = e*16 + n
    int e = li >> 4, n = li & 15;
    const float* W = isQ ? Wq : Wk;
    const float* w = isQ ? attn_w : attn_w + HDIM;
    const float* wp = &W[(size_t)e*EMB + n*HDIM];
    float s = 0.f;
    #pragma unroll 16
    for (int d = 0; d < HDIM; ++d) s = fmaf(wp[d], w[d], s);
    (isQ ? uq : uk)[li] = s;
  } else if (threadIdx.x < 16) {
    int n = threadIdx.x;
    float s = 0.f;
    for (int d = 0; d < HDIM; ++d) s = fmaf(bq[n*HDIM+d], attn_w[d], s);
    cq[n] = s;
  }
}

// ---------- sq = q @ uq + cq ; sk = k @ uk  (thin GEMM, one block per row) ----------
__global__ __launch_bounds__(256) void sqsk_kernel(
    const float* __restrict__ q, const float* __restrict__ k,
    const float* __restrict__ uq, const float* __restrict__ uk,
    const float* __restrict__ cq, float* __restrict__ sq, float* __restrict__ sk)
{
  __shared__ float rowbuf[EMB];
  __shared__ float part[16][17];
  int bid = blockIdx.x;
  bool isQ = bid < ROWS;
  int row = isQ ? bid : bid - ROWS;
  const float* X = isQ ? q : k;
  const float* U = isQ ? uq : uk;
  int tid = threadIdx.x;
  *reinterpret_cast<float4*>(&rowbuf[tid*4]) =
      *reinterpret_cast<const float4*>(&X[(size_t)row*EMB + tid*4]);
  __syncthreads();
  int n = tid & 15, ch = tid >> 4;
  float s = 0.f;
  #pragma unroll 8
  for (int e0 = 0; e0 < 64; ++e0) {
    int e = ch*64 + e0;
    s = fmaf(rowbuf[e], U[e*16 + n], s);
  }
  part[ch][n] = s;
  __syncthreads();
  if (tid < 16) {
    float t = isQ ? cq[tid] : 0.f;
    #pragma unroll
    for (int c = 0; c < 16; ++c) t += part[c][tid];
    (isQ ? sq : sk)[(size_t)row*16 + tid] = t;
  }
}

// ---------- per (b,n): min/max of sq -> 32 Chebyshev nodes ----------
__global__ __launch_bounds__(256) void nodes_kernel(const float* __restrict__ sq,
                                                    float* __restrict__ nodes)
{
  int bn = blockIdx.x;            // b*16+n
  int b = bn >> 4, n = bn & 15;
  int tid = threadIdx.x;
  float mn = 1e30f, mx = -1e30f;
  #pragma unroll
  for (int s = 0; s < 4; ++s) {
    float v = sq[((size_t)(b*SEQ + tid + s*256))*16 + n];
    mn = fminf(mn, v); mx = fmaxf(mx, v);
  }
  __shared__ float smn[256], smx[256];
  smn[tid] = mn; smx[tid] = mx;
  __syncthreads();
  for (int off = 128; off > 0; off >>= 1) {
    if (tid < off) { smn[tid] = fminf(smn[tid], smn[tid+off]);
                     smx[tid] = fmaxf(smx[tid], smx[tid+off]); }
    __syncthreads();
  }
  if (tid < MN) {
    float c = 0.5f*(smn[0] + smx[0]);
    float r = fmaxf(0.5f*(smx[0] - smn[0]), 1e-4f);
    nodes[bn*MN + tid] = c + r * cosf(tid * (3.14159265358979323f / (MN-1)));
  }
}

// ---------- weight prep: transpose + fp16 split  WT[n][k] = W[k][n] ----------
__global__ __launch_bounds__(256) void wprep_kernel(
    const float* __restrict__ Wv, const float* __restrict__ Wp,
    f16* __restrict__ WvTh, f16* __restrict__ WvTl,
    f16* __restrict__ WpTh, f16* __restrict__ WpTl)
{
  __shared__ float tile[64][65];
  const float* W = blockIdx.z ? Wp : Wv;
  f16* Th = blockIdx.z ? WpTh : WvTh;
  f16* Tl = blockIdx.z ? WpTl : WvTl;
  int k0 = blockIdx.y * 64, n0 = blockIdx.x * 64;
  int t = threadIdx.x, rr = t >> 4, c4 = (t & 15) * 4;
  #pragma unroll
  for (int i = 0; i < 4; ++i) {
    int row = rr + i * 16;
    float4 w = *reinterpret_cast<const float4*>(&W[(size_t)(k0 + row) * EMB + n0 + c4]);
    tile[row][c4] = w.x; tile[row][c4+1] = w.y;
    tile[row][c4+2] = w.z; tile[row][c4+3] = w.w;
  }
  __syncthreads();
  #pragma unroll
  for (int i = 0; i < 4; ++i) {
    int nn = rr + i * 16;
    f16x4 hh, ll;
    #pragma unroll
    for (int jj = 0; jj < 4; ++jj) {
      float x = tile[c4 + jj][nn];
      f16 h = (f16)x;
      hh[jj] = h;
      ll[jj] = (f16)(x - (float)h);
    }
    *reinterpret_cast<f16x4*>(&Th[(size_t)(n0 + nn) * EMB + k0 + c4]) = hh;
    *reinterpret_cast<f16x4*>(&Tl[(size_t)(n0 + nn) * EMB + k0 + c4]) = ll;
  }
}

// ---------- elementwise fp16 split of v ----------
__global__ __launch_bounds__(256) void split_kernel(
    const float* __restrict__ in, f16* __restrict__ h, f16* __restrict__ l)
{
  size_t i = ((size_t)blockIdx.x * 256 + threadIdx.x) * 4;
  float4 x = *reinterpret_cast<const float4*>(&in[i]);
  float xs[4] = {x.x, x.y, x.z, x.w};
  f16x4 hh, ll;
  #pragma unroll
  for (int jj = 0; jj < 4; ++jj) {
    f16 hv = (f16)xs[jj];
    hh[jj] = hv;
    ll[jj] = (f16)(xs[jj] - (float)hv);
  }
  *reinterpret_cast<f16x4*>(&h[i]) = hh;
  *reinterpret_cast<f16x4*>(&l[i]) = ll;
}

// ---------- fp16 split-3 MFMA GEMM: C = A @ B^T' (B given transposed [N][K]) ----------
// tile 128x64, BK=64, 4 waves (2x2), global_load_lds staging, XOR-swizzled LDS
#define GBM 128
#define GBN 64
#define GBK 64

__global__ __launch_bounds__(256) void gemm_split(
    const f16* __restrict__ Ah, const f16* __restrict__ Al,
    const f16* __restrict__ Bh, const f16* __restrict__ Bl,
    const float* __restrict__ bias, float* __restrict__ C,
    int M, int N, int K, int hasBias)
{
  __shared__ __align__(16) char lds[49152];   // Ah 16K | Al 16K | Bh 8K | Bl 8K
  const int tid = threadIdx.x;
  const int wid = tid >> 6, lane = tid & 63;
  const int brow = blockIdx.y * GBM;
  const int bcol = blockIdx.x * GBN;
  const int wm = wid >> 1, wn = wid & 1;
  const int asel = lane >> 4;
  const int l15 = lane & 15;

  f32x4 acc[4][2];
  #pragma unroll
  for (int i = 0; i < 4; ++i)
    #pragma unroll
    for (int jx = 0; jx < 2; ++jx)
      acc[i][jx] = (f32x4){0.f, 0.f, 0.f, 0.f};

  const int NT = K / GBK;
  for (int t = 0; t < NT; ++t) {
    const int k0 = t * GBK;
    __syncthreads();
    // stage: 12 rounds x 256 lanes x 16B. LDS dest linear; global source
    // pre-swizzled so that reads below (kc ^ (row&7)) see the right data.
    #pragma unroll
    for (int r = 0; r < 12; ++r) {
      const char* src;
      if (r < 8) {
        int ci = ((r & 3) << 8) + tid;        // chunk in A array
        int row = ci >> 3, kc = ci & 7;
        int kcg = kc ^ (row & 7);
        const f16* base = (r < 4) ? Ah : Al;
        src = (const char*)(base + (size_t)(brow + row) * K + k0 + kcg * 8);
      } else {
        int ci = ((r & 1) << 8) + tid;        // chunk in B array
        int col = ci >> 3, kc = ci & 7;
        int kcg = kc ^ (col & 7);
        const f16* base = (r < 10) ? Bh : Bl;
        src = (const char*)(base + (size_t)(bcol + col) * K + k0 + kcg * 8);
      }
      char* dst = lds + (r * 256 + wid * 64) * 16;
      __builtin_amdgcn_global_load_lds(
          (const __attribute__((address_space(1))) unsigned int*)src,
          (__attribute__((address_space(3))) unsigned int*)dst, 16, 0, 0);
    }
    __syncthreads();   // compiler drains vmcnt(0) here -> tile ready
    #pragma unroll
    for (int kk = 0; kk < 2; ++kk) {
      f16x8 afh[4], afl[4], bfh[2], bfl[2];
      #pragma unroll
      for (int mf = 0; mf < 4; ++mf) {
        int row = wm * 64 + mf * 16 + l15;
        int kcx = (kk * 4 + asel) ^ (row & 7);
        int off = row * 128 + kcx * 16;
        afh[mf] = *reinterpret_cast<const f16x8*>(lds + off);
        afl[mf] = *reinterpret_cast<const f16x8*>(lds + 16384 + off);
      }
      #pragma unroll
      for (int nf = 0; nf < 2; ++nf) {
        int col = wn * 32 + nf * 16 + l15;
        int kcx = (kk * 4 + asel) ^ (col & 7);
        int off = col * 128 + kcx * 16;
        bfh[nf] = *reinterpret_cast<const f16x8*>(lds + 32768 + off);
        bfl[nf] = *reinterpret_cast<const f16x8*>(lds + 40960 + off);
      }
      #pragma unroll
      for (int mf = 0; mf < 4; ++mf)
        #pragma unroll
        for (int nf = 0; nf < 2; ++nf) {
          acc[mf][nf] = __builtin_amdgcn_mfma_f32_16x16x32_f16(afh[mf], bfh[nf], acc[mf][nf], 0, 0, 0);
          acc[mf][nf] = __builtin_amdgcn_mfma_f32_16x16x32_f16(afh[mf], bfl[nf], acc[mf][nf], 0, 0, 0);
          acc[mf][nf] = __builtin_amdgcn_mfma_f32_16x16x32_f16(afl[mf], bfh[nf], acc[mf][nf], 0, 0, 0);
        }
    }
  }
  // epilogue: C/D layout col=lane&15, row=(lane>>4)*4+j
  const int crow0 = brow + wm * 64 + asel * 4;
  const int ccol0 = bcol + wn * 32 + l15;
  #pragma unroll
  for (int nf = 0; nf < 2; ++nf) {
    float bv = hasBias ? bias[ccol0 + nf * 16] : 0.f;
    #pragma unroll
    for (int mf = 0; mf < 4; ++mf)
      #pragma unroll
      for (int jx = 0; jx < 4; ++jx)
        C[(size_t)(crow0 + mf * 16 + jx) * N + ccol0 + nf * 16] = acc[mf][nf][jx] + bv;
  }
}

// ---------- G accumulation, LDS-staged: G[bn][m][d] += sum_j w(m,j) * [vh;1] ----------
__global__ __launch_bounds__(256) void gaccum2_kernel(
    const float* __restrict__ sk, const float* __restrict__ vh,
    const float* __restrict__ nodes, float* __restrict__ G)
{
  __shared__ float sksh[128];
  __shared__ float nsh[32];
  __shared__ float wsh[32 * 132];               // padded stride vs 128
  __shared__ __align__(16) float vtile[128 * 64];
  const int bn = blockIdx.y, b = bn >> 4, n = bn & 15;
  const int j0 = blockIdx.x * 128;
  const int tid = threadIdx.x;
  if (tid < 128) sksh[tid] = sk[(size_t)(b * SEQ + j0 + tid) * 16 + n];
  else if (tid < 160) nsh[tid - 128] = nodes[bn * MN + (tid - 128)];
  #pragma unroll
  for (int i = 0; i < 8; ++i) {
    int fi = tid + i * 256;
    int row = fi >> 4, c4 = (fi & 15) * 4;
    *reinterpret_cast<float4*>(&vtile[row * 64 + c4]) =
        *reinterpret_cast<const float4*>(&vh[(size_t)(b * SEQ + j0 + row) * EMB + n * HDIM + c4]);
  }
  __syncthreads();
  {
    int mw = tid >> 3;
    int jb = (tid & 7) * 16;
    float nm = nsh[mw];
    #pragma unroll
    for (int i = 0; i < 16; ++i) {
      int j = jb + i;
      float s = nm + sksh[j];
      float e2 = __expf(2.f * s);
      float th = 1.f - 2.f / (e2 + 1.f);        // tanh(s), inf-safe
      wsh[mw * 132 + j] = __expf(th);
    }
  }
  __syncthreads();
  const int m = tid >> 3, g = tid & 7;
  float4 a0 = make_float4(0,0,0,0), a1 = make_float4(0,0,0,0);
  float accw = 0.f;
  const float* wrow = &wsh[m * 132];
  #pragma unroll 4
  for (int j = 0; j < 128; ++j) {
    float w = wrow[j];
    float4 va = *reinterpret_cast<const float4*>(&vtile[j * 64 + g * 8]);
    float4 vb = *reinterpret_cast<const float4*>(&vtile[j * 64 + g * 8 + 4]);
    a0.x = fmaf(w, va.x, a0.x); a0.y = fmaf(w, va.y, a0.y);
    a0.z = fmaf(w, va.z, a0.z); a0.w = fmaf(w, va.w, a0.w);
    a1.x = fmaf(w, vb.x, a1.x); a1.y = fmaf(w, vb.y, a1.y);
    a1.z = fmaf(w, vb.z, a1.z); a1.w = fmaf(w, vb.w, a1.w);
    accw += w;
  }
  float* Gp = &G[((size_t)bn * MN + m) * 65];
  atomicAdd(&Gp[g*8+0], a0.x); atomicAdd(&Gp[g*8+1], a0.y);
  atomicAdd(&Gp[g*8+2], a0.z); atomicAdd(&Gp[g*8+3], a0.w);
  atomicAdd(&Gp[g*8+4], a1.x); atomicAdd(&Gp[g*8+5], a1.y);
  atomicAdd(&Gp[g*8+6], a1.z); atomicAdd(&Gp[g*8+7], a1.w);
  if (g == 0) atomicAdd(&Gp[64], accw);
}

// ---------- coeff: normalized barycentric coefficients c[bn][i][m], f16 h/l split ----------
__global__ __launch_bounds__(256) void coeff_kernel(
    const float* __restrict__ sq, const float* __restrict__ nodes,
    const float* __restrict__ G, f16* __restrict__ ch, f16* __restrict__ cl)
{
  __shared__ float nsh[MN], Wsh[MN];
  const int blk = blockIdx.x;            // 4 blocks per bn
  const int bn = blk >> 2;
  const int b = bn >> 4, n = bn & 15;
  const int i = (blk & 3) * 256 + threadIdx.x;   // row within bn
  if (threadIdx.x < MN) {
    nsh[threadIdx.x] = nodes[bn*MN + threadIdx.x];
    Wsh[threadIdx.x] = G[((size_t)bn*MN + threadIdx.x)*65 + 64];
  }
  __syncthreads();
  float s = sq[((size_t)b*SEQ + i)*16 + n];
  float lam[MN];
  float den = 0.f;
  int ex = -1;
  #pragma unroll
  for (int m = 0; m < MN; ++m) {
    float diff = s - nsh[m];
    float wb = ((m == 0) | (m == MN-1)) ? 0.5f : 1.0f;
    wb = (m & 1) ? -wb : wb;
    if (diff == 0.f) ex = m;
    lam[m] = wb / diff;
    den = fmaf(lam[m], Wsh[m], den);
  }
  float rden = 1.f / den;
  f16* chp = &ch[((size_t)bn*SEQ + i)*MN];
  f16* clp = &cl[((size_t)bn*SEQ + i)*MN];
  #pragma unroll
  for (int m8 = 0; m8 < 4; ++m8) {
    f16x8 hv, lv;
    #pragma unroll
    for (int j = 0; j < 8; ++j) {
      int m = m8*8 + j;
      float c = (ex >= 0) ? ((m == ex) ? 1.f/Wsh[ex] : 0.f) : lam[m]*rden;
      f16 h = (f16)c;
      hv[j] = h;
      lv[j] = (f16)(c - (float)h);
    }
    *reinterpret_cast<f16x8*>(&chp[m8*8]) = hv;
    *reinterpret_cast<f16x8*>(&clp[m8*8]) = lv;
  }
}

// ---------- gprep: G -> MFMA B-fragment order, f16 h/l split ----------
// Bfrag[bn][nf][lane] packs j=0..7 of Gh[m=(lane>>4)*8+j][nf*16+(lane&15)]
__global__ __launch_bounds__(256) void gprep_kernel(
    const float* __restrict__ G, f16* __restrict__ Bh, f16* __restrict__ Bl)
{
  const int bn = blockIdx.x;
  const int tid = threadIdx.x;
  const int nf = tid >> 6, lane = tid & 63;
  const int asel = lane >> 4, cd = lane & 15;
  f16x8 hv, lv;
  #pragma unroll
  for (int j = 0; j < 8; ++j) {
    int m = asel*8 + j;
    float g = G[((size_t)bn*MN + m)*65 + nf*16 + cd];
    f16 h = (f16)g;
    hv[j] = h;
    lv[j] = (f16)(g - (float)h);
  }
  size_t o = (((size_t)bn*4 + nf)*64 + lane)*8;
  *reinterpret_cast<f16x8*>(&Bh[o]) = hv;
  *reinterpret_cast<f16x8*>(&Bl[o]) = lv;
}

// ---------- interp via MFMA: attn[b,i,n*64+d] = sum_m c[bn][i][m] * G[bn][m][d] ----------
__global__ __launch_bounds__(256) void interp_mfma_kernel(
    const f16* __restrict__ ch, const f16* __restrict__ cl,
    const f16* __restrict__ Bh, const f16* __restrict__ Bl,
    f16* __restrict__ ah, f16* __restrict__ al)
{
  const int bn = blockIdx.y, chunk = blockIdx.x;   // chunk: 256 rows
  const int b = bn >> 4, n = bn & 15;
  const int tid = threadIdx.x;
  const int w = tid >> 6, lane = tid & 63;
  const int asel = lane >> 4, l15 = lane & 15;
  const int i0 = chunk*256 + w*64;                 // wave's first row
  f16x8 bh[4], bl[4];
  #pragma unroll
  for (int nf = 0; nf < 4; ++nf) {
    size_t o = (((size_t)bn*4 + nf)*64 + lane)*8;
    bh[nf] = *reinterpret_cast<const f16x8*>(&Bh[o]);
    bl[nf] = *reinterpret_cast<const f16x8*>(&Bl[o]);
  }
  #pragma unroll
  for (int mf = 0; mf < 4; ++mf) {
    int rowb = i0 + mf*16;
    size_t ao = ((size_t)bn*SEQ + rowb + l15)*MN + asel*8;
    f16x8 ahf = *reinterpret_cast<const f16x8*>(&ch[ao]);
    f16x8 alf = *reinterpret_cast<const f16x8*>(&cl[ao]);
    #pragma unroll
    for (int nf = 0; nf < 4; ++nf) {
      f32x4 acc = (f32x4){0.f, 0.f, 0.f, 0.f};
      acc = __builtin_amdgcn_mfma_f32_16x16x32_f16(ahf, bh[nf], acc, 0, 0, 0);
      acc = __builtin_amdgcn_mfma_f32_16x16x32_f16(ahf, bl[nf], acc, 0, 0, 0);
      acc = __builtin_amdgcn_mfma_f32_16x16x32_f16(alf, bh[nf], acc, 0, 0, 0);
      #pragma unroll
      for (int jx = 0; jx < 4; ++jx) {
        int r = rowb + asel*4 + jx;
        float v = acc[jx];
        f16 hv = (f16)v;
        size_t oidx = ((size_t)(b*SEQ + r))*EMB + n*HDIM + nf*16 + l15;
        ah[oidx] = hv;
        al[oidx] = (f16)(v - (float)hv);
      }
    }
  }
}

// ---------- row LayerNorm in-place on d_out ----------
__global__ __launch_bounds__(256) void ln_kernel(
    float* __restrict__ out, const float* __restrict__ gamma,
    const float* __restrict__ beta)
{
  int row = blockIdx.x, tid = threadIdx.x;
  float4 x = *reinterpret_cast<float4*>(&out[(size_t)row*EMB + tid*4]);
  float sum = x.x + x.y + x.z + x.w;
  float ssq = x.x*x.x + x.y*x.y + x.z*x.z + x.w*x.w;
  #pragma unroll
  for (int off = 32; off > 0; off >>= 1) {
    sum += __shfl_down(sum, off);
    ssq += __shfl_down(ssq, off);
  }
  __shared__ float red[8];
  int wave = tid >> 6, lane = tid & 63;
  if (lane == 0) { red[wave] = sum; red[4+wave] = ssq; }
  __syncthreads();
  if (tid == 0) {
    float a = red[0]+red[1]+red[2]+red[3];
    float qq = red[4]+red[5]+red[6]+red[7];
    float mean = a * (1.f/EMB);
    float var  = qq * (1.f/EMB) - mean*mean;
    red[0] = mean;
    red[1] = 1.0f / sqrtf(var + 1e-6f);
  }
  __syncthreads();
  float mean = red[0], inv = red[1];
  float4 gv = *reinterpret_cast<const float4*>(&gamma[tid*4]);
  float4 bv = *reinterpret_cast<const float4*>(&beta[tid*4]);
  x.x = (x.x - mean)*inv*gv.x + bv.x;
  x.y = (x.y - mean)*inv*gv.y + bv.y;
  x.z = (x.z - mean)*inv*gv.z + bv.z;
  x.w = (x.w - mean)*inv*gv.w + bv.w;
  *reinterpret_cast<float4*>(&out[(size_t)row*EMB + tid*4]) = x;
}

extern "C" void kernel_launch(void* const* d_in, const int* in_sizes, int n_in,
                              void* d_out, int out_size, void* d_ws, size_t ws_size,
                              hipStream_t stream)
{
  const float* k   = (const float*)d_in[0];
  const float* q   = (const float*)d_in[1];
  const float* v   = (const float*)d_in[2];
  const float* Wq  = (const float*)d_in[3];
  const float* bq  = (const float*)d_in[4];
  const float* Wk  = (const float*)d_in[5];
  const float* Wv  = (const float*)d_in[6];
  const float* Wp  = (const float*)d_in[7];
  const float* bp  = (const float*)d_in[8];
  const float* aw  = (const float*)d_in[9];
  const float* gamma = (const float*)d_in[10];
  const float* beta  = (const float*)d_in[11];
  float* out = (float*)d_out;

  float* ws   = (float*)d_ws;
  float* uq   = ws;                        // 16384
  float* uk   = uq + 16384;                // 16384
  float* cq   = uk + 16384;                // 16
  float* sq   = cq + 16;                   // 65536
  float* sk   = sq + 65536;                // 65536
  float* nodes= sk + 65536;                // 2048
  float* G    = nodes + 2048;              // 64*32*65 = 133120
  float* vh   = G + 133120;                // 4194304 f32
  f16* vsh    = (f16*)(vh + 4194304);      // 4194304 f16
  f16* vsl    = vsh + 4194304;             // 4194304 f16
  f16* WvTh   = vsl + 4194304;             // 1048576 f16
  f16* WvTl   = WvTh + 1048576;
  f16* WpTh   = WvTl + 1048576;
  f16* WpTl   = WpTh + 1048576;
  f16* ath    = vsh;                       // alias: v splits consumed by gemm1
  f16* atl    = vsl;
  // alias into vh region (vh consumed by gaccum2 before these are written):
  f16* ch     = (f16*)vh;                  // 64*1024*32 = 2097152 f16
  f16* cl     = ch + 2097152;              // 2097152 f16
  f16* Bfh    = cl + 2097152;              // 64*4*64*8 = 131072 f16
  f16* Bfl    = Bfh + 131072;              // 131072 f16

  // 1. fold attention weights into uq/uk/cq
  fold_kernel<<<129, 256, 0, stream>>>(Wq, Wk, bq, aw, uq, uk, cq);
  // 2. sq / sk thin GEMMs
  sqsk_kernel<<<2*ROWS, 256, 0, stream>>>(q, k, uq, uk, cq, sq, sk);
  // 3. Chebyshev nodes per (b,n)
  nodes_kernel<<<64, 256, 0, stream>>>(sq, nodes);
  // 4. zero G
  hipMemsetAsync(G, 0, (size_t)64*MN*65*sizeof(float), stream);
  // 5. weight transpose+split, v split
  wprep_kernel<<<dim3(16,16,2), 256, 0, stream>>>(Wv, Wp, WvTh, WvTl, WpTh, WpTl);
  split_kernel<<<4096, 256, 0, stream>>>(v, vsh, vsl);
  // 6. vh = v @ Wv   (fp16 split-3 MFMA)
  gemm_split<<<dim3(16,32), 256, 0, stream>>>(vsh, vsl, WvTh, WvTl, nullptr, vh,
                                              ROWS, EMB, EMB, 0);
  // 7. accumulate G
  gaccum2_kernel<<<dim3(8,64), 256, 0, stream>>>(sk, vh, nodes, G);
  // 8a. barycentric coefficients (per task), f16 split
  coeff_kernel<<<256, 256, 0, stream>>>(sq, nodes, G, ch, cl);
  // 8b. G -> B-fragment order, f16 split
  gprep_kernel<<<64, 256, 0, stream>>>(G, Bfh, Bfl);
  // 8c. interpolation as MFMA GEMM -> attn splits
  interp_mfma_kernel<<<dim3(4,64), 256, 0, stream>>>(ch, cl, Bfh, Bfl, ath, atl);
  // 9. out = attn @ Wp + bp   (fp16 split-3 MFMA)
  gemm_split<<<dim3(16,32), 256, 0, stream>>>(ath, atl, WpTh, WpTl, bp, out,
                                              ROWS, EMB, EMB, 1);
  // 10. LayerNorm in-place
  ln_kernel<<<ROWS, 256, 0, stream>>>(out, gamma, beta);
}

// Round 4
// 265.965 us; speedup vs baseline: 2.1165x; 1.0643x over previous
//
#include <hip/hip_runtime.h>
#include <math.h>

#define HEADS 16
#define HDIM  64
#define SEQ   1024
#define ROWS  4096
#define EMB   1024
#define MN    32

typedef _Float16 f16;
typedef __attribute__((ext_vector_type(4))) _Float16 f16x4;
typedef __attribute__((ext_vector_type(8))) _Float16 f16x8;
typedef __attribute__((ext_vector_type(4))) float f32x4;

// ---------- fold: uq[e*16+n] = Wq[e, n*64:].w1 ; uk likewise w2 ; cq[n] = bq.w1 ----------
__global__ __launch_bounds__(256) void fold_kernel(
    const float* __restrict__ Wq, const float* __restrict__ Wk,
    const float* __restrict__ bq, const float* __restrict__ attn_w,
    float* __restrict__ uq, float* __restrict__ uk, float* __restrict__ cq)
{
  int bid = blockIdx.x;
  if (bid < 128) {
    int idx = bid*256 + threadIdx.x;
    bool isQ = idx < 16384;
    int li = isQ ? idx : idx - 16384;      // li = e*16 + n
    int e = li >> 4, n = li & 15;
    const float* W = isQ ? Wq : Wk;
    const float* w = isQ ? attn_w : attn_w + HDIM;
    const float* wp = &W[(size_t)e*EMB + n*HDIM];
    float s = 0.f;
    #pragma unroll 16
    for (int d = 0; d < HDIM; ++d) s = fmaf(wp[d], w[d], s);
    (isQ ? uq : uk)[li] = s;
  } else if (threadIdx.x < 16) {
    int n = threadIdx.x;
    float s = 0.f;
    for (int d = 0; d < HDIM; ++d) s = fmaf(bq[n*HDIM+d], attn_w[d], s);
    cq[n] = s;
  }
}

// ---------- sq/sk: 8 rows per block (amortize U L2 traffic) ----------
__global__ __launch_bounds__(256) void sqsk2_kernel(
    const float* __restrict__ q, const float* __restrict__ k,
    const float* __restrict__ uq, const float* __restrict__ uk,
    const float* __restrict__ cq, float* __restrict__ sq, float* __restrict__ sk)
{
  __shared__ float rowbuf[8][EMB];
  __shared__ float part[16][8][17];
  int bid = blockIdx.x;
  bool isQ = bid < 512;
  int row0 = (isQ ? bid : bid - 512) * 8;
  const float* X = isQ ? q : k;
  const float* U = isQ ? uq : uk;
  int tid = threadIdx.x;
  #pragma unroll
  for (int p = 0; p < 8; ++p) {
    int fi = p*256 + tid;                 // float4 index within 8x1024
    int r = fi >> 8, c4 = (fi & 255) * 4;
    *reinterpret_cast<float4*>(&rowbuf[r][c4]) =
        *reinterpret_cast<const float4*>(&X[(size_t)(row0 + r)*EMB + c4]);
  }
  __syncthreads();
  int n = tid & 15, ch = tid >> 4;
  float acc[8] = {0,0,0,0,0,0,0,0};
  #pragma unroll 4
  for (int e0 = 0; e0 < 64; ++e0) {
    int e = ch*64 + e0;
    float u = U[e*16 + n];
    #pragma unroll
    for (int r = 0; r < 8; ++r) acc[r] = fmaf(rowbuf[r][e], u, acc[r]);
  }
  #pragma unroll
  for (int r = 0; r < 8; ++r) part[ch][r][n] = acc[r];
  __syncthreads();
  if (tid < 128) {
    int r = tid >> 4, nn = tid & 15;
    float t = isQ ? cq[nn] : 0.f;
    #pragma unroll
    for (int c = 0; c < 16; ++c) t += part[c][r][nn];
    (isQ ? sq : sk)[(size_t)(row0 + r)*16 + nn] = t;
  }
}

// ---------- per (b,n): min/max of sq -> 32 Chebyshev nodes ----------
__global__ __launch_bounds__(256) void nodes_kernel(const float* __restrict__ sq,
                                                    float* __restrict__ nodes)
{
  int bn = blockIdx.x;
  int b = bn >> 4, n = bn & 15;
  int tid = threadIdx.x;
  float mn = 1e30f, mx = -1e30f;
  #pragma unroll
  for (int s = 0; s < 4; ++s) {
    float v = sq[((size_t)(b*SEQ + tid + s*256))*16 + n];
    mn = fminf(mn, v); mx = fmaxf(mx, v);
  }
  __shared__ float smn[256], smx[256];
  smn[tid] = mn; smx[tid] = mx;
  __syncthreads();
  for (int off = 128; off > 0; off >>= 1) {
    if (tid < off) { smn[tid] = fminf(smn[tid], smn[tid+off]);
                     smx[tid] = fmaxf(smx[tid], smx[tid+off]); }
    __syncthreads();
  }
  if (tid < MN) {
    float c = 0.5f*(smn[0] + smx[0]);
    float r = fmaxf(0.5f*(smx[0] - smn[0]), 1e-4f);
    nodes[bn*MN + tid] = c + r * cosf(tid * (3.14159265358979323f / (MN-1)));
  }
}

// ---------- Wv transpose + fp16 split:  WvT[nd][e] = Wv[e][nd] ----------
__global__ __launch_bounds__(256) void wprepv_kernel(
    const float* __restrict__ Wv, f16* __restrict__ Th, f16* __restrict__ Tl)
{
  __shared__ float tile[64][65];
  int k0 = blockIdx.y * 64, n0 = blockIdx.x * 64;
  int t = threadIdx.x, rr = t >> 4, c4 = (t & 15) * 4;
  #pragma unroll
  for (int i = 0; i < 4; ++i) {
    int row = rr + i * 16;
    float4 w = *reinterpret_cast<const float4*>(&Wv[(size_t)(k0 + row) * EMB + n0 + c4]);
    tile[row][c4] = w.x; tile[row][c4+1] = w.y;
    tile[row][c4+2] = w.z; tile[row][c4+3] = w.w;
  }
  __syncthreads();
  #pragma unroll
  for (int i = 0; i < 4; ++i) {
    int nn = rr + i * 16;
    f16x4 hh, ll;
    #pragma unroll
    for (int jj = 0; jj < 4; ++jj) {
      float x = tile[c4 + jj][nn];
      f16 h = (f16)x;
      hh[jj] = h; ll[jj] = (f16)(x - (float)h);
    }
    *reinterpret_cast<f16x4*>(&Th[(size_t)(n0 + nn) * EMB + k0 + c4]) = hh;
    *reinterpret_cast<f16x4*>(&Tl[(size_t)(n0 + nn) * EMB + k0 + c4]) = ll;
  }
}

// ---------- v transpose + fp16 split: vT[b][e][j] = v[b][j][e] ----------
__global__ __launch_bounds__(256) void vtrans_kernel(
    const float* __restrict__ v, f16* __restrict__ Th, f16* __restrict__ Tl)
{
  __shared__ float tile[64][65];
  int b = blockIdx.z;
  int j0 = blockIdx.y * 64, e0 = blockIdx.x * 64;
  int t = threadIdx.x, rr = t >> 4, c4 = (t & 15) * 4;
  #pragma unroll
  for (int i = 0; i < 4; ++i) {
    int row = rr + i * 16;   // j_local
    float4 w = *reinterpret_cast<const float4*>(
        &v[((size_t)(b*SEQ + j0 + row))*EMB + e0 + c4]);
    tile[row][c4] = w.x; tile[row][c4+1] = w.y;
    tile[row][c4+2] = w.z; tile[row][c4+3] = w.w;
  }
  __syncthreads();
  #pragma unroll
  for (int i = 0; i < 4; ++i) {
    int el = rr + i * 16;
    f16x4 hh, ll;
    #pragma unroll
    for (int jj = 0; jj < 4; ++jj) {
      float x = tile[c4 + jj][el];
      f16 h = (f16)x;
      hh[jj] = h; ll[jj] = (f16)(x - (float)h);
    }
    size_t o = ((size_t)(b*EMB + e0 + el))*SEQ + j0 + c4;
    *reinterpret_cast<f16x4*>(&Th[o]) = hh;
    *reinterpret_cast<f16x4*>(&Tl[o]) = ll;
  }
}

// ---------- wmat: w[(b*512+n*32+m)][j] = exp(tanh(node+sk)) f16 split; Wn[bn*32+m]=sum_j w ----------
__global__ __launch_bounds__(256) void wmat_kernel(
    const float* __restrict__ sk, const float* __restrict__ nodes,
    f16* __restrict__ wh, f16* __restrict__ wl, float* __restrict__ Wn)
{
  __shared__ float sksh[256], nodesh[32], Wnl[32];
  const int qd = blockIdx.x, n = blockIdx.y, b = blockIdx.z;
  const int tid = threadIdx.x;
  const int j = qd*256 + tid;
  sksh[tid] = sk[((size_t)(b*SEQ + j))*16 + n];
  if (tid < 32) { nodesh[tid] = nodes[(b*16+n)*MN + tid]; Wnl[tid] = 0.f; }
  __syncthreads();
  const float skv = sksh[tid];
  const int lane = tid & 63;
  #pragma unroll 4
  for (int m = 0; m < 32; ++m) {
    float s = nodesh[m] + skv;
    float e2 = __expf(2.f * s);
    float th = 1.f - 2.f / (e2 + 1.f);
    float w = __expf(th);
    f16 h = (f16)w;
    size_t row = (size_t)(b*512 + n*32 + m);
    wh[row*1024 + j] = h;
    wl[row*1024 + j] = (f16)(w - (float)h);
    // wave reduce then LDS accumulate
    float ws = w;
    #pragma unroll
    for (int off = 32; off > 0; off >>= 1) ws += __shfl_xor(ws, off);
    if (lane == 0) atomicAdd(&Wnl[m], ws);
  }
  __syncthreads();
  if (tid < 32) atomicAdd(&Wn[(b*16+n)*32 + tid], Wnl[tid]);
}

// ---------- batched fp16 split-3 MFMA GEMM: C_z = A_z @ B_z^T' ----------
// tile 128x64, BK=64, 4 waves, global_load_lds, XOR-swizzled LDS (pre-swizzled source)
__global__ __launch_bounds__(256) void gemm_batched(
    const f16* __restrict__ Ah, const f16* __restrict__ Al,
    const f16* __restrict__ Bh, const f16* __restrict__ Bl,
    const float* __restrict__ bias, float* __restrict__ Cf,
    f16* __restrict__ Ch, f16* __restrict__ Cl,
    int MZ, int N, int K)
{
  __shared__ __align__(16) char lds[49152];   // Ah 16K | Al 16K | Bh 8K | Bl 8K
  const int tid = threadIdx.x;
  const int wid = tid >> 6, lane = tid & 63;
  const int z = blockIdx.z;
  const int brow = blockIdx.y * 128;          // local row within batch
  const int bcol = blockIdx.x * 64;
  const int wm = wid >> 1, wn = wid & 1;
  const int asel = lane >> 4;
  const int l15 = lane & 15;
  const f16* Az_h = Ah + (size_t)z*MZ*K;
  const f16* Az_l = Al + (size_t)z*MZ*K;
  const f16* Bz_h = Bh + (size_t)z*N*K;
  const f16* Bz_l = Bl + (size_t)z*N*K;

  f32x4 acc[4][2];
  #pragma unroll
  for (int i = 0; i < 4; ++i)
    #pragma unroll
    for (int jx = 0; jx < 2; ++jx)
      acc[i][jx] = (f32x4){0.f, 0.f, 0.f, 0.f};

  const int NT = K / 64;
  for (int t = 0; t < NT; ++t) {
    const int k0 = t * 64;
    __syncthreads();
    #pragma unroll
    for (int r = 0; r < 12; ++r) {
      const char* src;
      if (r < 8) {
        int ci = ((r & 3) << 8) + tid;
        int row = ci >> 3, kc = ci & 7;
        int kcg = kc ^ (row & 7);
        const f16* base = (r < 4) ? Az_h : Az_l;
        src = (const char*)(base + (size_t)(brow + row) * K + k0 + kcg * 8);
      } else {
        int ci = ((r & 1) << 8) + tid;
        int col = ci >> 3, kc = ci & 7;
        int kcg = kc ^ (col & 7);
        const f16* base = (r < 10) ? Bz_h : Bz_l;
        src = (const char*)(base + (size_t)(bcol + col) * K + k0 + kcg * 8);
      }
      char* dst = lds + (r * 256 + wid * 64) * 16;
      __builtin_amdgcn_global_load_lds(
          (const __attribute__((address_space(1))) unsigned int*)src,
          (__attribute__((address_space(3))) unsigned int*)dst, 16, 0, 0);
    }
    __syncthreads();
    #pragma unroll
    for (int kk = 0; kk < 2; ++kk) {
      f16x8 afh[4], afl[4], bfh[2], bfl[2];
      #pragma unroll
      for (int mf = 0; mf < 4; ++mf) {
        int row = wm * 64 + mf * 16 + l15;
        int kcx = (kk * 4 + asel) ^ (row & 7);
        int off = row * 128 + kcx * 16;
        afh[mf] = *reinterpret_cast<const f16x8*>(lds + off);
        afl[mf] = *reinterpret_cast<const f16x8*>(lds + 16384 + off);
      }
      #pragma unroll
      for (int nf = 0; nf < 2; ++nf) {
        int col = wn * 32 + nf * 16 + l15;
        int kcx = (kk * 4 + asel) ^ (col & 7);
        int off = col * 128 + kcx * 16;
        bfh[nf] = *reinterpret_cast<const f16x8*>(lds + 32768 + off);
        bfl[nf] = *reinterpret_cast<const f16x8*>(lds + 40960 + off);
      }
      #pragma unroll
      for (int mf = 0; mf < 4; ++mf)
        #pragma unroll
        for (int nf = 0; nf < 2; ++nf) {
          acc[mf][nf] = __builtin_amdgcn_mfma_f32_16x16x32_f16(afh[mf], bfh[nf], acc[mf][nf], 0, 0, 0);
          acc[mf][nf] = __builtin_amdgcn_mfma_f32_16x16x32_f16(afh[mf], bfl[nf], acc[mf][nf], 0, 0, 0);
          acc[mf][nf] = __builtin_amdgcn_mfma_f32_16x16x32_f16(afl[mf], bfh[nf], acc[mf][nf], 0, 0, 0);
        }
    }
  }
  const int crow0 = z*MZ + brow + wm * 64 + asel * 4;
  const int ccol0 = bcol + wn * 32 + l15;
  if (Ch) {
    #pragma unroll
    for (int nf = 0; nf < 2; ++nf)
      #pragma unroll
      for (int mf = 0; mf < 4; ++mf)
        #pragma unroll
        for (int jx = 0; jx < 4; ++jx) {
          float vv = acc[mf][nf][jx];
          f16 h = (f16)vv;
          size_t o = (size_t)(crow0 + mf*16 + jx) * N + ccol0 + nf*16;
          Ch[o] = h;
          Cl[o] = (f16)(vv - (float)h);
        }
  } else {
    #pragma unroll
    for (int nf = 0; nf < 2; ++nf) {
      float bv = bias ? bias[ccol0 + nf * 16] : 0.f;
      #pragma unroll
      for (int mf = 0; mf < 4; ++mf)
        #pragma unroll
        for (int jx = 0; jx < 4; ++jx)
          Cf[(size_t)(crow0 + mf*16 + jx) * N + ccol0 + nf*16] = acc[mf][nf][jx] + bv;
    }
  }
}

// ---------- gfin: G[bn*32+m][d] = P[bn*32+m][:] . WvT[n*64+d][:]  (MFMA split-3) ----------
__global__ __launch_bounds__(256) void gfin_kernel(
    const f16* __restrict__ Ph, const f16* __restrict__ Pl,
    const f16* __restrict__ WvTh, const f16* __restrict__ WvTl,
    float* __restrict__ G)
{
  const int bn = blockIdx.x, n = bn & 15;
  const int w = threadIdx.x >> 6, lane = threadIdx.x & 63;
  const int l15 = lane & 15, asel = lane >> 4;
  f32x4 acc[2];
  acc[0] = (f32x4){0.f,0.f,0.f,0.f};
  acc[1] = (f32x4){0.f,0.f,0.f,0.f};
  #pragma unroll 4
  for (int ks = 0; ks < 32; ++ks) {
    size_t bo = ((size_t)(n*64 + w*16 + l15))*1024 + ks*32 + asel*8;
    f16x8 bh = *reinterpret_cast<const f16x8*>(&WvTh[bo]);
    f16x8 bl = *reinterpret_cast<const f16x8*>(&WvTl[bo]);
    #pragma unroll
    for (int mf = 0; mf < 2; ++mf) {
      size_t ao = ((size_t)(bn*32 + mf*16 + l15))*1024 + ks*32 + asel*8;
      f16x8 ah = *reinterpret_cast<const f16x8*>(&Ph[ao]);
      f16x8 al = *reinterpret_cast<const f16x8*>(&Pl[ao]);
      acc[mf] = __builtin_amdgcn_mfma_f32_16x16x32_f16(ah, bh, acc[mf], 0, 0, 0);
      acc[mf] = __builtin_amdgcn_mfma_f32_16x16x32_f16(ah, bl, acc[mf], 0, 0, 0);
      acc[mf] = __builtin_amdgcn_mfma_f32_16x16x32_f16(al, bh, acc[mf], 0, 0, 0);
    }
  }
  #pragma unroll
  for (int mf = 0; mf < 2; ++mf)
    #pragma unroll
    for (int jx = 0; jx < 4; ++jx)
      G[(size_t)(bn*32 + mf*16 + asel*4 + jx)*64 + w*16 + l15] = acc[mf][jx];
}

// ---------- coeff: cs[b][i][n*32+m] = 1024 * normalized barycentric coeff, f16 split ----------
__global__ __launch_bounds__(256) void coeff2_kernel(
    const float* __restrict__ sq, const float* __restrict__ nodes,
    const float* __restrict__ Wn, f16* __restrict__ csh, f16* __restrict__ csl)
{
  __shared__ float nsh[16][32], wsh[16][32];
  const int ic = blockIdx.x, b = blockIdx.y;
  const int tid = threadIdx.x;
  for (int p = tid; p < 512; p += 256) {
    int nn = p >> 5, mm = p & 31;
    nsh[nn][mm] = nodes[(b*16+nn)*MN + mm];
    wsh[nn][mm] = Wn[(b*16+nn)*32 + mm];
  }
  __syncthreads();
  const int il = tid >> 4, n = tid & 15;
  const int i = ic*16 + il;
  float s = sq[((size_t)(b*SEQ + i))*16 + n];
  float lam[MN];
  float den = 0.f;
  int ex = -1;
  #pragma unroll
  for (int m = 0; m < MN; ++m) {
    float diff = s - nsh[n][m];
    float wb = ((m == 0) | (m == MN-1)) ? 0.5f : 1.0f;
    wb = (m & 1) ? -wb : wb;
    if (diff == 0.f) ex = m;
    lam[m] = wb / diff;
    den = fmaf(lam[m], wsh[n][m], den);
  }
  float rden = 1024.f / den;
  f16* hp = &csh[((size_t)(b*SEQ + i))*512 + n*32];
  f16* lp = &csl[((size_t)(b*SEQ + i))*512 + n*32];
  #pragma unroll
  for (int m8 = 0; m8 < 4; ++m8) {
    f16x8 hv, lv;
    #pragma unroll
    for (int jj = 0; jj < 8; ++jj) {
      int m = m8*8 + jj;
      float c = (ex >= 0) ? ((m == ex) ? 1024.f/wsh[n][ex] : 0.f) : lam[m]*rden;
      f16 h = (f16)c;
      hv[jj] = h; lv[jj] = (f16)(c - (float)h);
    }
    *reinterpret_cast<f16x8*>(&hp[m8*8]) = hv;
    *reinterpret_cast<f16x8*>(&lp[m8*8]) = lv;
  }
}

// ---------- hprep: Hs[b][o][n*32+m] = 2^-10 * sum_d G[bn*32+m][d] * Wp[n*64+d][o] ----------
__global__ __launch_bounds__(256) void hprep_kernel(
    const float* __restrict__ G, const float* __restrict__ Wp,
    f16* __restrict__ Hsh, f16* __restrict__ Hsl)
{
  __shared__ float Gsh[32][64];
  const int oc = blockIdx.x, n = blockIdx.y, b = blockIdx.z;
  const int bn = b*16 + n;
  const int tid = threadIdx.x;
  for (int p = tid; p < 2048; p += 256) {
    int m = p >> 6, d = p & 63;
    Gsh[m][d] = G[(size_t)(bn*32 + m)*64 + d];
  }
  __syncthreads();
  const int o = oc*256 + tid;
  float acc[32];
  #pragma unroll
  for (int m = 0; m < 32; ++m) acc[m] = 0.f;
  for (int d = 0; d < 64; ++d) {
    float wp = Wp[(size_t)(n*64 + d)*1024 + o];
    #pragma unroll
    for (int m = 0; m < 32; ++m) acc[m] = fmaf(wp, Gsh[m][d], acc[m]);
  }
  f16 hbuf[32], lbuf[32];
  #pragma unroll
  for (int m = 0; m < 32; ++m) {
    float vv = acc[m] * (1.f/1024.f);
    f16 h = (f16)vv;
    hbuf[m] = h; lbuf[m] = (f16)(vv - (float)h);
  }
  size_t base = ((size_t)(b*1024 + o))*512 + n*32;
  #pragma unroll
  for (int m8 = 0; m8 < 4; ++m8) {
    *reinterpret_cast<f16x8*>(&Hsh[base + m8*8]) = *reinterpret_cast<f16x8*>(&hbuf[m8*8]);
    *reinterpret_cast<f16x8*>(&Hsl[base + m8*8]) = *reinterpret_cast<f16x8*>(&lbuf[m8*8]);
  }
}

// ---------- row LayerNorm in-place on d_out ----------
__global__ __launch_bounds__(256) void ln_kernel(
    float* __restrict__ out, const float* __restrict__ gamma,
    const float* __restrict__ beta)
{
  int row = blockIdx.x, tid = threadIdx.x;
  float4 x = *reinterpret_cast<float4*>(&out[(size_t)row*EMB + tid*4]);
  float sum = x.x + x.y + x.z + x.w;
  float ssq = x.x*x.x + x.y*x.y + x.z*x.z + x.w*x.w;
  #pragma unroll
  for (int off = 32; off > 0; off >>= 1) {
    sum += __shfl_down(sum, off);
    ssq += __shfl_down(ssq, off);
  }
  __shared__ float red[8];
  int wave = tid >> 6, lane = tid & 63;
  if (lane == 0) { red[wave] = sum; red[4+wave] = ssq; }
  __syncthreads();
  if (tid == 0) {
    float a = red[0]+red[1]+red[2]+red[3];
    float qq = red[4]+red[5]+red[6]+red[7];
    float mean = a * (1.f/EMB);
    float var  = qq * (1.f/EMB) - mean*mean;
    red[0] = mean;
    red[1] = 1.0f / sqrtf(var + 1e-6f);
  }
  __syncthreads();
  float mean = red[0], inv = red[1];
  float4 gv = *reinterpret_cast<const float4*>(&gamma[tid*4]);
  float4 bv = *reinterpret_cast<const float4*>(&beta[tid*4]);
  x.x = (x.x - mean)*inv*gv.x + bv.x;
  x.y = (x.y - mean)*inv*gv.y + bv.y;
  x.z = (x.z - mean)*inv*gv.z + bv.z;
  x.w = (x.w - mean)*inv*gv.w + bv.w;
  *reinterpret_cast<float4*>(&out[(size_t)row*EMB + tid*4]) = x;
}

extern "C" void kernel_launch(void* const* d_in, const int* in_sizes, int n_in,
                              void* d_out, int out_size, void* d_ws, size_t ws_size,
                              hipStream_t stream)
{
  const float* k   = (const float*)d_in[0];
  const float* q   = (const float*)d_in[1];
  const float* v   = (const float*)d_in[2];
  const float* Wq  = (const float*)d_in[3];
  const float* bq  = (const float*)d_in[4];
  const float* Wk  = (const float*)d_in[5];
  const float* Wv  = (const float*)d_in[6];
  const float* Wp  = (const float*)d_in[7];
  const float* bp  = (const float*)d_in[8];
  const float* aw  = (const float*)d_in[9];
  const float* gamma = (const float*)d_in[10];
  const float* beta  = (const float*)d_in[11];
  float* out = (float*)d_out;

  float* ws    = (float*)d_ws;
  float* uq    = ws;                    // 16384
  float* uk    = uq + 16384;            // 16384
  float* cq    = uk + 16384;            // 16
  float* sq    = cq + 16;               // 65536
  float* sk    = sq + 65536;            // 65536
  float* nodes = sk + 65536;            // 2048
  float* Wn    = nodes + 2048;          // 2048
  float* G     = Wn + 2048;             // 64*32*64 = 131072
  // f32 end: 299024 floats = 1,196,096 B (16B aligned)
  const size_t MEG = 1048576;
  f16* f16b  = (f16*)(ws + 299024);
  f16* WvTh  = f16b;                    // 1M f16
  f16* WvTl  = f16b + 1*MEG;            // 1M
  f16* Ph    = f16b + 2*MEG;            // 2M
  f16* Pl    = f16b + 4*MEG;            // 2M
  f16* vTh   = f16b + 6*MEG;            // 4M
  f16* vTl   = f16b + 10*MEG;           // 4M
  f16* wh    = f16b + 14*MEG;           // 2M
  f16* wl    = f16b + 16*MEG;           // 2M  -> end 18M f16 (36MB)
  // phase-2 aliases (dead after gemm1):
  f16* csh   = f16b + 6*MEG;            // 2M  (alias vTh)
  f16* csl   = f16b + 8*MEG;            // 2M
  f16* Hsh   = f16b + 10*MEG;           // 2M  (alias vTl)
  f16* Hsl   = f16b + 12*MEG;           // 2M

  // 1. fold attention weights
  fold_kernel<<<129, 256, 0, stream>>>(Wq, Wk, bq, aw, uq, uk, cq);
  // 2. sq / sk (8 rows per block)
  sqsk2_kernel<<<1024, 256, 0, stream>>>(q, k, uq, uk, cq, sq, sk);
  // 3. Chebyshev nodes
  nodes_kernel<<<64, 256, 0, stream>>>(sq, nodes);
  // 4. Wv transpose+split ; v transpose+split
  wprepv_kernel<<<dim3(16,16), 256, 0, stream>>>(Wv, WvTh, WvTl);
  vtrans_kernel<<<dim3(16,16,4), 256, 0, stream>>>(v, vTh, vTl);
  // 5. w matrix + row sums
  hipMemsetAsync(Wn, 0, 2048*sizeof(float), stream);
  wmat_kernel<<<dim3(4,16,4), 256, 0, stream>>>(sk, nodes, wh, wl, Wn);
  // 6. P = w @ v^T  (batched per b; M=512,N=1024,K=1024) -> f16 split
  gemm_batched<<<dim3(16,4,4), 256, 0, stream>>>(wh, wl, vTh, vTl,
      nullptr, nullptr, Ph, Pl, 512, 1024, 1024);
  // 7. coefficients (alias region now free)
  coeff2_kernel<<<dim3(64,4), 256, 0, stream>>>(sq, nodes, Wn, csh, csl);
  // 8. G = P @ WvT
  gfin_kernel<<<64, 256, 0, stream>>>(Ph, Pl, WvTh, WvTl, G);
  // 9. Hs = (G @ Wp) * 2^-10, transposed to [o][nm], f16 split
  hprep_kernel<<<dim3(4,16,4), 256, 0, stream>>>(G, Wp, Hsh, Hsl);
  // 10. out = cs @ Hs^T' + bp  (batched per b; M=1024,N=1024,K=512)
  gemm_batched<<<dim3(16,8,4), 256, 0, stream>>>(csh, csl, Hsh, Hsl,
      bp, out, nullptr, nullptr, 1024, 1024, 512);
  // 11. LayerNorm in-place
  ln_kernel<<<ROWS, 256, 0, stream>>>(out, gamma, beta);
}

// Round 5
// 228.980 us; speedup vs baseline: 2.4584x; 1.1615x over previous
//
#include <hip/hip_runtime.h>
#include <math.h>

#define HEADS 16
#define HDIM  64
#define SEQ   1024
#define ROWS  4096
#define EMB   1024
#define MN    16     // Chebyshev nodes (error ~rho^-16 ~ 1e-5, << 2^-6 budget)

typedef _Float16 f16;
typedef __attribute__((ext_vector_type(4))) _Float16 f16x4;
typedef __attribute__((ext_vector_type(8))) _Float16 f16x8;
typedef __attribute__((ext_vector_type(4))) float f32x4;

// ---------- fold: uq[e*16+n] = Wq[e, n*64:].w1 ; uk likewise w2 ; cq[n] = bq.w1 ----------
__global__ __launch_bounds__(256) void fold_kernel(
    const float* __restrict__ Wq, const float* __restrict__ Wk,
    const float* __restrict__ bq, const float* __restrict__ attn_w,
    float* __restrict__ uq, float* __restrict__ uk, float* __restrict__ cq)
{
  int bid = blockIdx.x;
  if (bid < 128) {
    int idx = bid*256 + threadIdx.x;
    bool isQ = idx < 16384;
    int li = isQ ? idx : idx - 16384;      // li = e*16 + n
    int e = li >> 4, n = li & 15;
    const float* W = isQ ? Wq : Wk;
    const float* w = isQ ? attn_w : attn_w + HDIM;
    const float* wp = &W[(size_t)e*EMB + n*HDIM];
    float s = 0.f;
    #pragma unroll 16
    for (int d = 0; d < HDIM; ++d) s = fmaf(wp[d], w[d], s);
    (isQ ? uq : uk)[li] = s;
  } else if (threadIdx.x < 16) {
    int n = threadIdx.x;
    float s = 0.f;
    for (int d = 0; d < HDIM; ++d) s = fmaf(bq[n*HDIM+d], attn_w[d], s);
    cq[n] = s;
  }
}

// ---------- sq/sk: 8 rows per block ----------
__global__ __launch_bounds__(256) void sqsk2_kernel(
    const float* __restrict__ q, const float* __restrict__ k,
    const float* __restrict__ uq, const float* __restrict__ uk,
    const float* __restrict__ cq, float* __restrict__ sq, float* __restrict__ sk)
{
  __shared__ float rowbuf[8][EMB];
  __shared__ float part[16][8][17];
  int bid = blockIdx.x;
  bool isQ = bid < 512;
  int row0 = (isQ ? bid : bid - 512) * 8;
  const float* X = isQ ? q : k;
  const float* U = isQ ? uq : uk;
  int tid = threadIdx.x;
  #pragma unroll
  for (int p = 0; p < 8; ++p) {
    int fi = p*256 + tid;
    int r = fi >> 8, c4 = (fi & 255) * 4;
    *reinterpret_cast<float4*>(&rowbuf[r][c4]) =
        *reinterpret_cast<const float4*>(&X[(size_t)(row0 + r)*EMB + c4]);
  }
  __syncthreads();
  int n = tid & 15, ch = tid >> 4;
  float acc[8] = {0,0,0,0,0,0,0,0};
  #pragma unroll 4
  for (int e0 = 0; e0 < 64; ++e0) {
    int e = ch*64 + e0;
    float u = U[e*16 + n];
    #pragma unroll
    for (int r = 0; r < 8; ++r) acc[r] = fmaf(rowbuf[r][e], u, acc[r]);
  }
  #pragma unroll
  for (int r = 0; r < 8; ++r) part[ch][r][n] = acc[r];
  __syncthreads();
  if (tid < 128) {
    int r = tid >> 4, nn = tid & 15;
    float t = isQ ? cq[nn] : 0.f;
    #pragma unroll
    for (int c = 0; c < 16; ++c) t += part[c][r][nn];
    (isQ ? sq : sk)[(size_t)(row0 + r)*16 + nn] = t;
  }
}

// ---------- per (b,n): min/max of sq -> MN Chebyshev-Lobatto nodes ----------
__global__ __launch_bounds__(256) void nodes_kernel(const float* __restrict__ sq,
                                                    float* __restrict__ nodes)
{
  int bn = blockIdx.x;
  int b = bn >> 4, n = bn & 15;
  int tid = threadIdx.x;
  float mn = 1e30f, mx = -1e30f;
  #pragma unroll
  for (int s = 0; s < 4; ++s) {
    float v = sq[((size_t)(b*SEQ + tid + s*256))*16 + n];
    mn = fminf(mn, v); mx = fmaxf(mx, v);
  }
  __shared__ float smn[256], smx[256];
  smn[tid] = mn; smx[tid] = mx;
  __syncthreads();
  for (int off = 128; off > 0; off >>= 1) {
    if (tid < off) { smn[tid] = fminf(smn[tid], smn[tid+off]);
                     smx[tid] = fmaxf(smx[tid], smx[tid+off]); }
    __syncthreads();
  }
  if (tid < MN) {
    float c = 0.5f*(smn[0] + smx[0]);
    float r = fmaxf(0.5f*(smx[0] - smn[0]), 1e-4f);
    nodes[bn*MN + tid] = c + r * cosf(tid * (3.14159265358979323f / (MN-1)));
  }
}

// ---------- Wv transpose + fp16 split ----------
__global__ __launch_bounds__(256) void wprepv_kernel(
    const float* __restrict__ Wv, f16* __restrict__ Th, f16* __restrict__ Tl)
{
  __shared__ float tile[64][65];
  int k0 = blockIdx.y * 64, n0 = blockIdx.x * 64;
  int t = threadIdx.x, rr = t >> 4, c4 = (t & 15) * 4;
  #pragma unroll
  for (int i = 0; i < 4; ++i) {
    int row = rr + i * 16;
    float4 w = *reinterpret_cast<const float4*>(&Wv[(size_t)(k0 + row) * EMB + n0 + c4]);
    tile[row][c4] = w.x; tile[row][c4+1] = w.y;
    tile[row][c4+2] = w.z; tile[row][c4+3] = w.w;
  }
  __syncthreads();
  #pragma unroll
  for (int i = 0; i < 4; ++i) {
    int nn = rr + i * 16;
    f16x4 hh, ll;
    #pragma unroll
    for (int jj = 0; jj < 4; ++jj) {
      float x = tile[c4 + jj][nn];
      f16 h = (f16)x;
      hh[jj] = h; ll[jj] = (f16)(x - (float)h);
    }
    *reinterpret_cast<f16x4*>(&Th[(size_t)(n0 + nn) * EMB + k0 + c4]) = hh;
    *reinterpret_cast<f16x4*>(&Tl[(size_t)(n0 + nn) * EMB + k0 + c4]) = ll;
  }
}

// ---------- v transpose + fp16 split: vT[b][e][j] = v[b][j][e] ----------
__global__ __launch_bounds__(256) void vtrans_kernel(
    const float* __restrict__ v, f16* __restrict__ Th, f16* __restrict__ Tl)
{
  __shared__ float tile[64][65];
  int b = blockIdx.z;
  int j0 = blockIdx.y * 64, e0 = blockIdx.x * 64;
  int t = threadIdx.x, rr = t >> 4, c4 = (t & 15) * 4;
  #pragma unroll
  for (int i = 0; i < 4; ++i) {
    int row = rr + i * 16;
    float4 w = *reinterpret_cast<const float4*>(
        &v[((size_t)(b*SEQ + j0 + row))*EMB + e0 + c4]);
    tile[row][c4] = w.x; tile[row][c4+1] = w.y;
    tile[row][c4+2] = w.z; tile[row][c4+3] = w.w;
  }
  __syncthreads();
  #pragma unroll
  for (int i = 0; i < 4; ++i) {
    int el = rr + i * 16;
    f16x4 hh, ll;
    #pragma unroll
    for (int jj = 0; jj < 4; ++jj) {
      float x = tile[c4 + jj][el];
      f16 h = (f16)x;
      hh[jj] = h; ll[jj] = (f16)(x - (float)h);
    }
    size_t o = ((size_t)(b*EMB + e0 + el))*SEQ + j0 + c4;
    *reinterpret_cast<f16x4*>(&Th[o]) = hh;
    *reinterpret_cast<f16x4*>(&Tl[o]) = ll;
  }
}

// ---------- wmat: w[(b*256+n*16+m)][j] = exp(tanh(node+sk)), f16 split; Wn = row sums ----------
__global__ __launch_bounds__(256) void wmat_kernel(
    const float* __restrict__ sk, const float* __restrict__ nodes,
    f16* __restrict__ wh, f16* __restrict__ wl, float* __restrict__ Wn)
{
  __shared__ float sksh[256], nodesh[MN], Wnl[MN];
  const int qd = blockIdx.x, n = blockIdx.y, b = blockIdx.z;
  const int tid = threadIdx.x;
  const int j = qd*256 + tid;
  sksh[tid] = sk[((size_t)(b*SEQ + j))*16 + n];
  if (tid < MN) { nodesh[tid] = nodes[(b*16+n)*MN + tid]; Wnl[tid] = 0.f; }
  __syncthreads();
  const float skv = sksh[tid];
  const int lane = tid & 63;
  #pragma unroll 4
  for (int m = 0; m < MN; ++m) {
    float s = nodesh[m] + skv;
    float e2 = __expf(2.f * s);
    float th = 1.f - 2.f / (e2 + 1.f);
    float w = __expf(th);
    f16 h = (f16)w;
    size_t row = (size_t)(b*256 + n*MN + m);
    wh[row*1024 + j] = h;
    wl[row*1024 + j] = (f16)(w - (float)h);
    float ws = w;
    #pragma unroll
    for (int off = 32; off > 0; off >>= 1) ws += __shfl_xor(ws, off);
    if (lane == 0) atomicAdd(&Wnl[m], ws);
  }
  __syncthreads();
  if (tid < MN) atomicAdd(&Wn[(b*16+n)*MN + tid], Wnl[tid]);
}

// ---------- gemm1: 64x64 tile, 4 waves; C[M=1024][N=1024] = wh/wl @ vT(batch)^T', K=1024 ----------
__global__ __launch_bounds__(256) void gemm1_64(
    const f16* __restrict__ Ah, const f16* __restrict__ Al,
    const f16* __restrict__ Bh, const f16* __restrict__ Bl,
    f16* __restrict__ Ch, f16* __restrict__ Cl)
{
  __shared__ __align__(16) char lds[32768];   // Ah 8K | Al 8K | Bh 8K | Bl 8K
  const int tid = threadIdx.x;
  const int wid = tid >> 6, lane = tid & 63;
  // XCD-bijective swizzle of 256 blocks
  int flat = blockIdx.y * 16 + blockIdx.x;
  int swz = (flat & 7) * 32 + (flat >> 3);
  const int bx = swz & 15, by = swz >> 4;
  const int z = by >> 2;                      // batch
  const int grow = by * 64;                   // global A/C row
  const int bcol = bx * 64;
  const int wm = wid >> 1, wn = wid & 1;
  const int asel = lane >> 4, l15 = lane & 15;
  const int K = 1024, N = 1024;
  const f16* Bz_h = Bh + (size_t)z*EMB*SEQ;
  const f16* Bz_l = Bl + (size_t)z*EMB*SEQ;

  f32x4 acc[2][2];
  #pragma unroll
  for (int i = 0; i < 2; ++i)
    #pragma unroll
    for (int jx = 0; jx < 2; ++jx)
      acc[i][jx] = (f32x4){0.f, 0.f, 0.f, 0.f};

  for (int t = 0; t < 16; ++t) {
    const int k0 = t * 64;
    __syncthreads();
    #pragma unroll
    for (int r = 0; r < 8; ++r) {
      int ci = ((r & 1) << 8) + tid;          // 0..511
      int row = ci >> 3, kc = ci & 7;
      int kcg = kc ^ (row & 7);
      const f16* base = (r < 2) ? Ah : (r < 4) ? Al : (r < 6) ? Bz_h : Bz_l;
      size_t roff = (r < 4) ? (size_t)(grow + row) : (size_t)(bcol + row);
      const char* src = (const char*)(base + roff * K + k0 + kcg * 8);
      char* dst = lds + (r * 512 + ci) * 16 - (r & 1) * 4096 * 0; // linear
      dst = lds + (r * 256 + wid * 64) * 16;
      __builtin_amdgcn_global_load_lds(
          (const __attribute__((address_space(1))) unsigned int*)src,
          (__attribute__((address_space(3))) unsigned int*)dst, 16, 0, 0);
    }
    __syncthreads();
    #pragma unroll
    for (int kk = 0; kk < 2; ++kk) {
      f16x8 afh[2], afl[2], bfh[2], bfl[2];
      #pragma unroll
      for (int mf = 0; mf < 2; ++mf) {
        int row = wm * 32 + mf * 16 + l15;
        int kcx = (kk * 4 + asel) ^ (row & 7);
        int off = row * 128 + kcx * 16;
        afh[mf] = *reinterpret_cast<const f16x8*>(lds + off);
        afl[mf] = *reinterpret_cast<const f16x8*>(lds + 8192 + off);
      }
      #pragma unroll
      for (int nf = 0; nf < 2; ++nf) {
        int col = wn * 32 + nf * 16 + l15;
        int kcx = (kk * 4 + asel) ^ (col & 7);
        int off = col * 128 + kcx * 16;
        bfh[nf] = *reinterpret_cast<const f16x8*>(lds + 16384 + off);
        bfl[nf] = *reinterpret_cast<const f16x8*>(lds + 24576 + off);
      }
      #pragma unroll
      for (int mf = 0; mf < 2; ++mf)
        #pragma unroll
        for (int nf = 0; nf < 2; ++nf) {
          acc[mf][nf] = __builtin_amdgcn_mfma_f32_16x16x32_f16(afh[mf], bfh[nf], acc[mf][nf], 0, 0, 0);
          acc[mf][nf] = __builtin_amdgcn_mfma_f32_16x16x32_f16(afh[mf], bfl[nf], acc[mf][nf], 0, 0, 0);
          acc[mf][nf] = __builtin_amdgcn_mfma_f32_16x16x32_f16(afl[mf], bfh[nf], acc[mf][nf], 0, 0, 0);
        }
    }
  }
  const int crow0 = grow + wm * 32 + asel * 4;
  const int ccol0 = bcol + wn * 32 + l15;
  #pragma unroll
  for (int nf = 0; nf < 2; ++nf)
    #pragma unroll
    for (int mf = 0; mf < 2; ++mf)
      #pragma unroll
      for (int jx = 0; jx < 4; ++jx) {
        float vv = acc[mf][nf][jx];
        f16 h = (f16)vv;
        size_t o = (size_t)(crow0 + mf*16 + jx) * N + ccol0 + nf*16;
        Ch[o] = h;
        Cl[o] = (f16)(vv - (float)h);
      }
}

// ---------- gemm2: 128x64 tile, batched; out = cs @ Hs^T' + bp, K=256 ----------
__global__ __launch_bounds__(256) void gemm2_k(
    const f16* __restrict__ Ah, const f16* __restrict__ Al,
    const f16* __restrict__ Bh, const f16* __restrict__ Bl,
    const float* __restrict__ bias, float* __restrict__ Cf)
{
  __shared__ __align__(16) char lds[49152];   // Ah 16K | Al 16K | Bh 8K | Bl 8K
  const int tid = threadIdx.x;
  const int wid = tid >> 6, lane = tid & 63;
  // bijective XCD swizzle of 512 blocks
  int flat = (blockIdx.z * 8 + blockIdx.y) * 16 + blockIdx.x;
  int swz = (flat & 7) * 64 + (flat >> 3);
  const int bx = swz & 15;
  const int t2 = swz >> 4;
  const int by = t2 & 7, z = t2 >> 3;
  const int brow = by * 128;
  const int bcol = bx * 64;
  const int wm = wid >> 1, wn = wid & 1;
  const int asel = lane >> 4, l15 = lane & 15;
  const int K = 256, N = 1024, MZ = 1024;
  const f16* Az_h = Ah + (size_t)z*MZ*K;
  const f16* Az_l = Al + (size_t)z*MZ*K;
  const f16* Bz_h = Bh + (size_t)z*N*K;
  const f16* Bz_l = Bl + (size_t)z*N*K;

  f32x4 acc[4][2];
  #pragma unroll
  for (int i = 0; i < 4; ++i)
    #pragma unroll
    for (int jx = 0; jx < 2; ++jx)
      acc[i][jx] = (f32x4){0.f, 0.f, 0.f, 0.f};

  for (int t = 0; t < 4; ++t) {
    const int k0 = t * 64;
    __syncthreads();
    #pragma unroll
    for (int r = 0; r < 12; ++r) {
      const char* src;
      if (r < 8) {
        int ci = ((r & 3) << 8) + tid;
        int row = ci >> 3, kc = ci & 7;
        int kcg = kc ^ (row & 7);
        const f16* base = (r < 4) ? Az_h : Az_l;
        src = (const char*)(base + (size_t)(brow + row) * K + k0 + kcg * 8);
      } else {
        int ci = ((r & 1) << 8) + tid;
        int col = ci >> 3, kc = ci & 7;
        int kcg = kc ^ (col & 7);
        const f16* base = (r < 10) ? Bz_h : Bz_l;
        src = (const char*)(base + (size_t)(bcol + col) * K + k0 + kcg * 8);
      }
      char* dst = lds + (r * 256 + wid * 64) * 16;
      __builtin_amdgcn_global_load_lds(
          (const __attribute__((address_space(1))) unsigned int*)src,
          (__attribute__((address_space(3))) unsigned int*)dst, 16, 0, 0);
    }
    __syncthreads();
    #pragma unroll
    for (int kk = 0; kk < 2; ++kk) {
      f16x8 afh[4], afl[4], bfh[2], bfl[2];
      #pragma unroll
      for (int mf = 0; mf < 4; ++mf) {
        int row = wm * 64 + mf * 16 + l15;
        int kcx = (kk * 4 + asel) ^ (row & 7);
        int off = row * 128 + kcx * 16;
        afh[mf] = *reinterpret_cast<const f16x8*>(lds + off);
        afl[mf] = *reinterpret_cast<const f16x8*>(lds + 16384 + off);
      }
      #pragma unroll
      for (int nf = 0; nf < 2; ++nf) {
        int col = wn * 32 + nf * 16 + l15;
        int kcx = (kk * 4 + asel) ^ (col & 7);
        int off = col * 128 + kcx * 16;
        bfh[nf] = *reinterpret_cast<const f16x8*>(lds + 32768 + off);
        bfl[nf] = *reinterpret_cast<const f16x8*>(lds + 40960 + off);
      }
      #pragma unroll
      for (int mf = 0; mf < 4; ++mf)
        #pragma unroll
        for (int nf = 0; nf < 2; ++nf) {
          acc[mf][nf] = __builtin_amdgcn_mfma_f32_16x16x32_f16(afh[mf], bfh[nf], acc[mf][nf], 0, 0, 0);
          acc[mf][nf] = __builtin_amdgcn_mfma_f32_16x16x32_f16(afh[mf], bfl[nf], acc[mf][nf], 0, 0, 0);
          acc[mf][nf] = __builtin_amdgcn_mfma_f32_16x16x32_f16(afl[mf], bfh[nf], acc[mf][nf], 0, 0, 0);
        }
    }
  }
  const int crow0 = z*MZ + brow + wm * 64 + asel * 4;
  const int ccol0 = bcol + wn * 32 + l15;
  #pragma unroll
  for (int nf = 0; nf < 2; ++nf) {
    float bv = bias[ccol0 + nf * 16];
    #pragma unroll
    for (int mf = 0; mf < 4; ++mf)
      #pragma unroll
      for (int jx = 0; jx < 4; ++jx)
        Cf[(size_t)(crow0 + mf*16 + jx) * N + ccol0 + nf*16] = acc[mf][nf][jx] + bv;
  }
}

// ---------- gfin: G[bn*16+m][d] = P-row . WvT-row  (MFMA split-3), K=1024 ----------
__global__ __launch_bounds__(256) void gfin_kernel(
    const f16* __restrict__ Ph, const f16* __restrict__ Pl,
    const f16* __restrict__ WvTh, const f16* __restrict__ WvTl,
    float* __restrict__ G)
{
  const int bn = blockIdx.x, n = bn & 15;
  const int w = threadIdx.x >> 6, lane = threadIdx.x & 63;
  const int l15 = lane & 15, asel = lane >> 4;
  f32x4 acc = (f32x4){0.f,0.f,0.f,0.f};
  #pragma unroll 4
  for (int ks = 0; ks < 32; ++ks) {
    size_t bo = ((size_t)(n*64 + w*16 + l15))*1024 + ks*32 + asel*8;
    f16x8 bh = *reinterpret_cast<const f16x8*>(&WvTh[bo]);
    f16x8 bl = *reinterpret_cast<const f16x8*>(&WvTl[bo]);
    size_t ao = ((size_t)(bn*MN + l15))*1024 + ks*32 + asel*8;
    f16x8 ah = *reinterpret_cast<const f16x8*>(&Ph[ao]);
    f16x8 al = *reinterpret_cast<const f16x8*>(&Pl[ao]);
    acc = __builtin_amdgcn_mfma_f32_16x16x32_f16(ah, bh, acc, 0, 0, 0);
    acc = __builtin_amdgcn_mfma_f32_16x16x32_f16(ah, bl, acc, 0, 0, 0);
    acc = __builtin_amdgcn_mfma_f32_16x16x32_f16(al, bh, acc, 0, 0, 0);
  }
  #pragma unroll
  for (int jx = 0; jx < 4; ++jx)
    G[(size_t)(bn*MN + asel*4 + jx)*64 + w*16 + l15] = acc[jx];
}

// ---------- coeff: cs[b][i][n*16+m] = 1024 * normalized barycentric coeff, f16 split ----------
__global__ __launch_bounds__(256) void coeff2_kernel(
    const float* __restrict__ sq, const float* __restrict__ nodes,
    const float* __restrict__ Wn, f16* __restrict__ csh, f16* __restrict__ csl)
{
  __shared__ float nsh[16][MN], wsh[16][MN];
  const int ic = blockIdx.x, b = blockIdx.y;
  const int tid = threadIdx.x;
  {
    int nn = tid >> 4, mm = tid & 15;
    nsh[nn][mm] = nodes[(b*16+nn)*MN + mm];
    wsh[nn][mm] = Wn[(b*16+nn)*MN + mm];
  }
  __syncthreads();
  const int il = tid >> 4, n = tid & 15;
  const int i = ic*16 + il;
  float s = sq[((size_t)(b*SEQ + i))*16 + n];
  float lam[MN];
  float den = 0.f;
  int ex = -1;
  #pragma unroll
  for (int m = 0; m < MN; ++m) {
    float diff = s - nsh[n][m];
    float wb = ((m == 0) | (m == MN-1)) ? 0.5f : 1.0f;
    wb = (m & 1) ? -wb : wb;
    if (diff == 0.f) ex = m;
    lam[m] = wb / diff;
    den = fmaf(lam[m], wsh[n][m], den);
  }
  float rden = 1024.f / den;
  f16* hp = &csh[((size_t)(b*SEQ + i))*256 + n*MN];
  f16* lp = &csl[((size_t)(b*SEQ + i))*256 + n*MN];
  #pragma unroll
  for (int m8 = 0; m8 < 2; ++m8) {
    f16x8 hv, lv;
    #pragma unroll
    for (int jj = 0; jj < 8; ++jj) {
      int m = m8*8 + jj;
      float c = (ex >= 0) ? ((m == ex) ? 1024.f/wsh[n][ex] : 0.f) : lam[m]*rden;
      f16 h = (f16)c;
      hv[jj] = h; lv[jj] = (f16)(c - (float)h);
    }
    *reinterpret_cast<f16x8*>(&hp[m8*8]) = hv;
    *reinterpret_cast<f16x8*>(&lp[m8*8]) = lv;
  }
}

// ---------- hprep: Hs[b][o][n*16+m] = 2^-10 * sum_d G[bn*16+m][d] * Wp[n*64+d][o] ----------
__global__ __launch_bounds__(256) void hprep_kernel(
    const float* __restrict__ G, const float* __restrict__ Wp,
    f16* __restrict__ Hsh, f16* __restrict__ Hsl)
{
  __shared__ float Gsh[MN][64];
  const int oc = blockIdx.x, n = blockIdx.y, b = blockIdx.z;
  const int bn = b*16 + n;
  const int tid = threadIdx.x;
  for (int p = tid; p < MN*64; p += 256) {
    int m = p >> 6, d = p & 63;
    Gsh[m][d] = G[(size_t)(bn*MN + m)*64 + d];
  }
  __syncthreads();
  const int o = oc*256 + tid;
  float acc[MN];
  #pragma unroll
  for (int m = 0; m < MN; ++m) acc[m] = 0.f;
  for (int d = 0; d < 64; ++d) {
    float wp = Wp[(size_t)(n*64 + d)*1024 + o];
    #pragma unroll
    for (int m = 0; m < MN; ++m) acc[m] = fmaf(wp, Gsh[m][d], acc[m]);
  }
  f16 hbuf[MN], lbuf[MN];
  #pragma unroll
  for (int m = 0; m < MN; ++m) {
    float vv = acc[m] * (1.f/1024.f);
    f16 h = (f16)vv;
    hbuf[m] = h; lbuf[m] = (f16)(vv - (float)h);
  }
  size_t base = ((size_t)(b*1024 + o))*256 + n*MN;
  #pragma unroll
  for (int m8 = 0; m8 < 2; ++m8) {
    *reinterpret_cast<f16x8*>(&Hsh[base + m8*8]) = *reinterpret_cast<f16x8*>(&hbuf[m8*8]);
    *reinterpret_cast<f16x8*>(&Hsl[base + m8*8]) = *reinterpret_cast<f16x8*>(&lbuf[m8*8]);
  }
}

// ---------- row LayerNorm in-place ----------
__global__ __launch_bounds__(256) void ln_kernel(
    float* __restrict__ out, const float* __restrict__ gamma,
    const float* __restrict__ beta)
{
  int row = blockIdx.x, tid = threadIdx.x;
  float4 x = *reinterpret_cast<float4*>(&out[(size_t)row*EMB + tid*4]);
  float sum = x.x + x.y + x.z + x.w;
  float ssq = x.x*x.x + x.y*x.y + x.z*x.z + x.w*x.w;
  #pragma unroll
  for (int off = 32; off > 0; off >>= 1) {
    sum += __shfl_down(sum, off);
    ssq += __shfl_down(ssq, off);
  }
  __shared__ float red[8];
  int wave = tid >> 6, lane = tid & 63;
  if (lane == 0) { red[wave] = sum; red[4+wave] = ssq; }
  __syncthreads();
  if (tid == 0) {
    float a = red[0]+red[1]+red[2]+red[3];
    float qq = red[4]+red[5]+red[6]+red[7];
    float mean = a * (1.f/EMB);
    float var  = qq * (1.f/EMB) - mean*mean;
    red[0] = mean;
    red[1] = 1.0f / sqrtf(var + 1e-6f);
  }
  __syncthreads();
  float mean = red[0], inv = red[1];
  float4 gv = *reinterpret_cast<const float4*>(&gamma[tid*4]);
  float4 bv = *reinterpret_cast<const float4*>(&beta[tid*4]);
  x.x = (x.x - mean)*inv*gv.x + bv.x;
  x.y = (x.y - mean)*inv*gv.y + bv.y;
  x.z = (x.z - mean)*inv*gv.z + bv.z;
  x.w = (x.w - mean)*inv*gv.w + bv.w;
  *reinterpret_cast<float4*>(&out[(size_t)row*EMB + tid*4]) = x;
}

extern "C" void kernel_launch(void* const* d_in, const int* in_sizes, int n_in,
                              void* d_out, int out_size, void* d_ws, size_t ws_size,
                              hipStream_t stream)
{
  const float* k   = (const float*)d_in[0];
  const float* q   = (const float*)d_in[1];
  const float* v   = (const float*)d_in[2];
  const float* Wq  = (const float*)d_in[3];
  const float* bq  = (const float*)d_in[4];
  const float* Wk  = (const float*)d_in[5];
  const float* Wv  = (const float*)d_in[6];
  const float* Wp  = (const float*)d_in[7];
  const float* bp  = (const float*)d_in[8];
  const float* aw  = (const float*)d_in[9];
  const float* gamma = (const float*)d_in[10];
  const float* beta  = (const float*)d_in[11];
  float* out = (float*)d_out;

  float* ws    = (float*)d_ws;
  float* uq    = ws;                    // 16384
  float* uk    = uq + 16384;            // 16384
  float* cq    = uk + 16384;            // 16
  float* sq    = cq + 16;               // 65536
  float* sk    = sq + 65536;            // 65536
  float* nodes = sk + 65536;            // 64*16 = 1024
  float* Wn    = nodes + 1024;          // 1024
  float* G     = Wn + 1024;             // 64*16*64 = 65536
  // f32 end: 231440 floats (925760 B, 16B-aligned)
  const size_t MEG = 1048576;
  f16* f16b  = (f16*)(ws + 231440);
  f16* WvTh  = f16b;                    // 1M f16
  f16* WvTl  = f16b + 1*MEG;            // 1M
  f16* Ph    = f16b + 2*MEG;            // 1M (1024x1024)
  f16* Pl    = f16b + 3*MEG;            // 1M
  f16* vTh   = f16b + 4*MEG;            // 4M
  f16* vTl   = f16b + 8*MEG;            // 4M
  f16* wh    = f16b + 12*MEG;           // 1M (1024x1024)
  f16* wl    = f16b + 13*MEG;           // 1M -> end 14M f16 (28MB)
  // phase-2 aliases (vT dead after gemm1):
  f16* csh   = f16b + 4*MEG;            // 1M (4096x256)
  f16* csl   = f16b + 5*MEG;            // 1M
  f16* Hsh   = f16b + 8*MEG;            // 1M (4096x256)
  f16* Hsl   = f16b + 9*MEG;            // 1M

  // 1. fold attention weights
  fold_kernel<<<129, 256, 0, stream>>>(Wq, Wk, bq, aw, uq, uk, cq);
  // 2. sq / sk
  sqsk2_kernel<<<1024, 256, 0, stream>>>(q, k, uq, uk, cq, sq, sk);
  // 3. Chebyshev nodes (MN=16)
  nodes_kernel<<<64, 256, 0, stream>>>(sq, nodes);
  // 4. Wv transpose+split ; v transpose+split
  wprepv_kernel<<<dim3(16,16), 256, 0, stream>>>(Wv, WvTh, WvTl);
  vtrans_kernel<<<dim3(16,16,4), 256, 0, stream>>>(v, vTh, vTl);
  // 5. w matrix + row sums
  hipMemsetAsync(Wn, 0, 1024*sizeof(float), stream);
  wmat_kernel<<<dim3(4,16,4), 256, 0, stream>>>(sk, nodes, wh, wl, Wn);
  // 6. P = w @ v^T  (M=1024 over 4 batches, 64x64 tiles, 256 blocks)
  gemm1_64<<<dim3(16,16), 256, 0, stream>>>(wh, wl, vTh, vTl, Ph, Pl);
  // 7. coefficients (aliases vT region, now dead)
  coeff2_kernel<<<dim3(64,4), 256, 0, stream>>>(sq, nodes, Wn, csh, csl);
  // 8. G = P @ WvT
  gfin_kernel<<<64, 256, 0, stream>>>(Ph, Pl, WvTh, WvTl, G);
  // 9. Hs = (G @ Wp) * 2^-10
  hprep_kernel<<<dim3(4,16,4), 256, 0, stream>>>(G, Wp, Hsh, Hsl);
  // 10. out = cs @ Hs^T' + bp  (K=256)
  gemm2_k<<<dim3(16,8,4), 256, 0, stream>>>(csh, csl, Hsh, Hsl, bp, out);
  // 11. LayerNorm in-place
  ln_kernel<<<ROWS, 256, 0, stream>>>(out, gamma, beta);
}

// Round 6
// 196.121 us; speedup vs baseline: 2.8703x; 1.1675x over previous
//
#include <hip/hip_runtime.h>
#include <math.h>

#define HEADS 16
#define HDIM  64
#define SEQ   1024
#define ROWS  4096
#define EMB   1024
#define MN    16     // Chebyshev nodes

typedef _Float16 f16;
typedef __attribute__((ext_vector_type(4))) _Float16 f16x4;
typedef __attribute__((ext_vector_type(8))) _Float16 f16x8;
typedef __attribute__((ext_vector_type(4))) float f32x4;

// ---------- fold: uq[e*16+n] = Wq[e, n*64:].w1 ; uk likewise w2 ; cq[n] = bq.w1 ----------
__global__ __launch_bounds__(256) void fold_kernel(
    const float* __restrict__ Wq, const float* __restrict__ Wk,
    const float* __restrict__ bq, const float* __restrict__ attn_w,
    float* __restrict__ uq, float* __restrict__ uk, float* __restrict__ cq)
{
  int bid = blockIdx.x;
  if (bid < 128) {
    int idx = bid*256 + threadIdx.x;
    bool isQ = idx < 16384;
    int li = isQ ? idx : idx - 16384;      // li = e*16 + n
    int e = li >> 4, n = li & 15;
    const float* W = isQ ? Wq : Wk;
    const float* w = isQ ? attn_w : attn_w + HDIM;
    const float* wp = &W[(size_t)e*EMB + n*HDIM];
    float s = 0.f;
    #pragma unroll 16
    for (int d = 0; d < HDIM; ++d) s = fmaf(wp[d], w[d], s);
    (isQ ? uq : uk)[li] = s;
  } else if (threadIdx.x < 16) {
    int n = threadIdx.x;
    float s = 0.f;
    for (int d = 0; d < HDIM; ++d) s = fmaf(bq[n*HDIM+d], attn_w[d], s);
    cq[n] = s;
  }
}

// ---------- sq/sk: 8 rows per block ----------
__global__ __launch_bounds__(256) void sqsk2_kernel(
    const float* __restrict__ q, const float* __restrict__ k,
    const float* __restrict__ uq, const float* __restrict__ uk,
    const float* __restrict__ cq, float* __restrict__ sq, float* __restrict__ sk)
{
  __shared__ float rowbuf[8][EMB];
  __shared__ float part[16][8][17];
  int bid = blockIdx.x;
  bool isQ = bid < 512;
  int row0 = (isQ ? bid : bid - 512) * 8;
  const float* X = isQ ? q : k;
  const float* U = isQ ? uq : uk;
  int tid = threadIdx.x;
  #pragma unroll
  for (int p = 0; p < 8; ++p) {
    int fi = p*256 + tid;
    int r = fi >> 8, c4 = (fi & 255) * 4;
    *reinterpret_cast<float4*>(&rowbuf[r][c4]) =
        *reinterpret_cast<const float4*>(&X[(size_t)(row0 + r)*EMB + c4]);
  }
  __syncthreads();
  int n = tid & 15, ch = tid >> 4;
  float acc[8] = {0,0,0,0,0,0,0,0};
  #pragma unroll 4
  for (int e0 = 0; e0 < 64; ++e0) {
    int e = ch*64 + e0;
    float u = U[e*16 + n];
    #pragma unroll
    for (int r = 0; r < 8; ++r) acc[r] = fmaf(rowbuf[r][e], u, acc[r]);
  }
  #pragma unroll
  for (int r = 0; r < 8; ++r) part[ch][r][n] = acc[r];
  __syncthreads();
  if (tid < 128) {
    int r = tid >> 4, nn = tid & 15;
    float t = isQ ? cq[nn] : 0.f;
    #pragma unroll
    for (int c = 0; c < 16; ++c) t += part[c][r][nn];
    (isQ ? sq : sk)[(size_t)(row0 + r)*16 + nn] = t;
  }
}

// ---------- per (b,n): min/max of sq -> MN Chebyshev-Lobatto nodes ----------
__global__ __launch_bounds__(256) void nodes_kernel(const float* __restrict__ sq,
                                                    float* __restrict__ nodes)
{
  int bn = blockIdx.x;
  int b = bn >> 4, n = bn & 15;
  int tid = threadIdx.x;
  float mn = 1e30f, mx = -1e30f;
  #pragma unroll
  for (int s = 0; s < 4; ++s) {
    float v = sq[((size_t)(b*SEQ + tid + s*256))*16 + n];
    mn = fminf(mn, v); mx = fmaxf(mx, v);
  }
  __shared__ float smn[256], smx[256];
  smn[tid] = mn; smx[tid] = mx;
  __syncthreads();
  for (int off = 128; off > 0; off >>= 1) {
    if (tid < off) { smn[tid] = fminf(smn[tid], smn[tid+off]);
                     smx[tid] = fmaxf(smx[tid], smx[tid+off]); }
    __syncthreads();
  }
  if (tid < MN) {
    float c = 0.5f*(smn[0] + smx[0]);
    float r = fmaxf(0.5f*(smx[0] - smn[0]), 1e-4f);
    nodes[bn*MN + tid] = c + r * cosf(tid * (3.14159265358979323f / (MN-1)));
  }
}

// ---------- ztrans: z<4 -> vT[b][e][j]=v[b][j][e] ; z==4 -> WvT[nd][e]=Wv[e][nd] (f16 h only) ----------
__global__ __launch_bounds__(256) void ztrans_kernel(
    const float* __restrict__ v, const float* __restrict__ Wv,
    f16* __restrict__ vTh, f16* __restrict__ WvTh)
{
  __shared__ float tile[64][65];
  const int z = blockIdx.z;
  const int r0 = blockIdx.y * 64, c0 = blockIdx.x * 64;
  const int t = threadIdx.x, rr = t >> 4, c4 = (t & 15) * 4;
  const float* src = (z < 4) ? &v[(size_t)(z*SEQ + r0)*EMB + c0]
                             : &Wv[(size_t)r0*EMB + c0];
  #pragma unroll
  for (int i = 0; i < 4; ++i) {
    int row = rr + i * 16;
    float4 w = *reinterpret_cast<const float4*>(&src[(size_t)row*EMB + c4]);
    tile[row][c4] = w.x; tile[row][c4+1] = w.y;
    tile[row][c4+2] = w.z; tile[row][c4+3] = w.w;
  }
  __syncthreads();
  #pragma unroll
  for (int i = 0; i < 4; ++i) {
    int cc = rr + i * 16;                 // transposed row = original col
    f16x4 hh;
    #pragma unroll
    for (int jj = 0; jj < 4; ++jj) hh[jj] = (f16)tile[c4 + jj][cc];
    size_t o = (z < 4) ? ((size_t)(z*EMB + c0 + cc))*SEQ + r0 + c4
                       : ((size_t)(c0 + cc))*EMB + r0 + c4;
    *reinterpret_cast<f16x4*>(&((z < 4) ? vTh : WvTh)[o]) = hh;
  }
}

// ---------- wmat: w[(b*256+n*16+m)][j] = exp(tanh(node+sk)) f16; Wn = row sums ----------
__global__ __launch_bounds__(256) void wmat_kernel(
    const float* __restrict__ sk, const float* __restrict__ nodes,
    f16* __restrict__ wh, float* __restrict__ Wn)
{
  __shared__ float sksh[256], nodesh[MN], Wnl[MN];
  const int qd = blockIdx.x, n = blockIdx.y, b = blockIdx.z;
  const int tid = threadIdx.x;
  const int j = qd*256 + tid;
  sksh[tid] = sk[((size_t)(b*SEQ + j))*16 + n];
  if (tid < MN) { nodesh[tid] = nodes[(b*16+n)*MN + tid]; Wnl[tid] = 0.f; }
  __syncthreads();
  const float skv = sksh[tid];
  const int lane = tid & 63;
  #pragma unroll 4
  for (int m = 0; m < MN; ++m) {
    float s = nodesh[m] + skv;
    float e2 = __expf(2.f * s);
    float th = 1.f - 2.f / (e2 + 1.f);
    float w = __expf(th);
    size_t row = (size_t)(b*256 + n*MN + m);
    wh[row*1024 + j] = (f16)w;
    float ws = w;
    #pragma unroll
    for (int off = 32; off > 0; off >>= 1) ws += __shfl_xor(ws, off);
    if (lane == 0) atomicAdd(&Wnl[m], ws);
  }
  __syncthreads();
  if (tid < MN) atomicAdd(&Wn[(b*16+n)*MN + tid], Wnl[tid]);
}

// ---------- gemm1 plain f16: P[1024][1024] = w @ vT(batch)^T', K=1024, 64x64 tiles ----------
__global__ __launch_bounds__(256) void gemm1_f16(
    const f16* __restrict__ Ah, const f16* __restrict__ Bh,
    f16* __restrict__ Ch)
{
  __shared__ __align__(16) char lds[16384];   // A 8K | B 8K
  const int tid = threadIdx.x;
  const int wid = tid >> 6, lane = tid & 63;
  int flat = blockIdx.y * 16 + blockIdx.x;
  int swz = (flat & 7) * 32 + (flat >> 3);    // bijective XCD swizzle, 256 blocks
  const int bx = swz & 15, by = swz >> 4;
  const int z = by >> 2;
  const int grow = by * 64;
  const int bcol = bx * 64;
  const int wm = wid >> 1, wn = wid & 1;
  const int asel = lane >> 4, l15 = lane & 15;
  const int K = 1024, N = 1024;
  const f16* Bz_h = Bh + (size_t)z*EMB*SEQ;

  f32x4 acc[2][2];
  #pragma unroll
  for (int i = 0; i < 2; ++i)
    #pragma unroll
    for (int jx = 0; jx < 2; ++jx)
      acc[i][jx] = (f32x4){0.f, 0.f, 0.f, 0.f};

  for (int t = 0; t < 16; ++t) {
    const int k0 = t * 64;
    __syncthreads();
    #pragma unroll
    for (int r = 0; r < 4; ++r) {
      int ci = ((r & 1) << 8) + tid;          // 0..511
      int row = ci >> 3, kc = ci & 7;
      int kcg = kc ^ (row & 7);
      const f16* base = (r < 2) ? Ah : Bz_h;
      size_t roff = (r < 2) ? (size_t)(grow + row) : (size_t)(bcol + row);
      const char* src = (const char*)(base + roff * K + k0 + kcg * 8);
      char* dst = lds + (r * 256 + wid * 64) * 16;
      __builtin_amdgcn_global_load_lds(
          (const __attribute__((address_space(1))) unsigned int*)src,
          (__attribute__((address_space(3))) unsigned int*)dst, 16, 0, 0);
    }
    __syncthreads();
    #pragma unroll
    for (int kk = 0; kk < 2; ++kk) {
      f16x8 afh[2], bfh[2];
      #pragma unroll
      for (int mf = 0; mf < 2; ++mf) {
        int row = wm * 32 + mf * 16 + l15;
        int kcx = (kk * 4 + asel) ^ (row & 7);
        afh[mf] = *reinterpret_cast<const f16x8*>(lds + row * 128 + kcx * 16);
      }
      #pragma unroll
      for (int nf = 0; nf < 2; ++nf) {
        int col = wn * 32 + nf * 16 + l15;
        int kcx = (kk * 4 + asel) ^ (col & 7);
        bfh[nf] = *reinterpret_cast<const f16x8*>(lds + 8192 + col * 128 + kcx * 16);
      }
      #pragma unroll
      for (int mf = 0; mf < 2; ++mf)
        #pragma unroll
        for (int nf = 0; nf < 2; ++nf)
          acc[mf][nf] = __builtin_amdgcn_mfma_f32_16x16x32_f16(afh[mf], bfh[nf], acc[mf][nf], 0, 0, 0);
    }
  }
  const int crow0 = grow + wm * 32 + asel * 4;
  const int ccol0 = bcol + wn * 32 + l15;
  #pragma unroll
  for (int nf = 0; nf < 2; ++nf)
    #pragma unroll
    for (int mf = 0; mf < 2; ++mf)
      #pragma unroll
      for (int jx = 0; jx < 4; ++jx)
        Ch[(size_t)(crow0 + mf*16 + jx) * N + ccol0 + nf*16] = (f16)acc[mf][nf][jx];
}

// ---------- coeff: cs[b][i][n*16+m] = 1024 * normalized barycentric coeff, f16 split ----------
__global__ __launch_bounds__(256) void coeff2_kernel(
    const float* __restrict__ sq, const float* __restrict__ nodes,
    const float* __restrict__ Wn, f16* __restrict__ csh, f16* __restrict__ csl)
{
  __shared__ float nsh[16][MN], wsh[16][MN];
  const int ic = blockIdx.x, b = blockIdx.y;
  const int tid = threadIdx.x;
  {
    int nn = tid >> 4, mm = tid & 15;
    nsh[nn][mm] = nodes[(b*16+nn)*MN + mm];
    wsh[nn][mm] = Wn[(b*16+nn)*MN + mm];
  }
  __syncthreads();
  const int il = tid >> 4, n = tid & 15;
  const int i = ic*16 + il;
  float s = sq[((size_t)(b*SEQ + i))*16 + n];
  float lam[MN];
  float den = 0.f;
  int ex = -1;
  #pragma unroll
  for (int m = 0; m < MN; ++m) {
    float diff = s - nsh[n][m];
    float wb = ((m == 0) | (m == MN-1)) ? 0.5f : 1.0f;
    wb = (m & 1) ? -wb : wb;
    if (diff == 0.f) ex = m;
    lam[m] = wb / diff;
    den = fmaf(lam[m], wsh[n][m], den);
  }
  float rden = 1024.f / den;
  f16* hp = &csh[((size_t)(b*SEQ + i))*256 + n*MN];
  f16* lp = &csl[((size_t)(b*SEQ + i))*256 + n*MN];
  #pragma unroll
  for (int m8 = 0; m8 < 2; ++m8) {
    f16x8 hv, lv;
    #pragma unroll
    for (int jj = 0; jj < 8; ++jj) {
      int m = m8*8 + jj;
      float c = (ex >= 0) ? ((m == ex) ? 1024.f/wsh[n][ex] : 0.f) : lam[m]*rden;
      f16 h = (f16)c;
      hv[jj] = h; lv[jj] = (f16)(c - (float)h);
    }
    *reinterpret_cast<f16x8*>(&hp[m8*8]) = hv;
    *reinterpret_cast<f16x8*>(&lp[m8*8]) = lv;
  }
}

// ---------- ghprep (fused gfin+hprep): G in LDS via MFMA, then Hs = (G@Wp)*2^-10 split ----------
__global__ __launch_bounds__(256) void ghprep_kernel(
    const f16* __restrict__ Ph, const f16* __restrict__ WvTh,
    const float* __restrict__ Wp, f16* __restrict__ Hsh, f16* __restrict__ Hsl)
{
  __shared__ float Gsh[MN][64];
  const int oc = blockIdx.x, n = blockIdx.y, b = blockIdx.z;
  const int bn = b*16 + n;
  const int tid = threadIdx.x;
  const int w = tid >> 6, lane = tid & 63;
  const int l15 = lane & 15, asel = lane >> 4;
  // step 1: G[m][w*16+l15] = P-row . WvT-row  (plain f16 MFMA, K=1024)
  f32x4 acc = (f32x4){0.f,0.f,0.f,0.f};
  #pragma unroll 4
  for (int ks = 0; ks < 32; ++ks) {
    size_t bo = ((size_t)(n*64 + w*16 + l15))*1024 + ks*32 + asel*8;
    f16x8 bh = *reinterpret_cast<const f16x8*>(&WvTh[bo]);
    size_t ao = ((size_t)(bn*MN + l15))*1024 + ks*32 + asel*8;
    f16x8 ah = *reinterpret_cast<const f16x8*>(&Ph[ao]);
    acc = __builtin_amdgcn_mfma_f32_16x16x32_f16(ah, bh, acc, 0, 0, 0);
  }
  #pragma unroll
  for (int jx = 0; jx < 4; ++jx)
    Gsh[asel*4 + jx][w*16 + l15] = acc[jx];
  __syncthreads();
  // step 2: per-o column of Wp, accumulate over d
  const int o = oc*256 + tid;
  float a2[MN];
  #pragma unroll
  for (int m = 0; m < MN; ++m) a2[m] = 0.f;
  for (int d = 0; d < 64; ++d) {
    float wp = Wp[(size_t)(n*64 + d)*1024 + o];
    #pragma unroll
    for (int m = 0; m < MN; ++m) a2[m] = fmaf(wp, Gsh[m][d], a2[m]);
  }
  f16 hbuf[MN], lbuf[MN];
  #pragma unroll
  for (int m = 0; m < MN; ++m) {
    float vv = a2[m] * (1.f/1024.f);
    f16 h = (f16)vv;
    hbuf[m] = h; lbuf[m] = (f16)(vv - (float)h);
  }
  size_t base = ((size_t)(b*1024 + o))*256 + n*MN;
  #pragma unroll
  for (int m8 = 0; m8 < 2; ++m8) {
    *reinterpret_cast<f16x8*>(&Hsh[base + m8*8]) = *reinterpret_cast<f16x8*>(&hbuf[m8*8]);
    *reinterpret_cast<f16x8*>(&Hsl[base + m8*8]) = *reinterpret_cast<f16x8*>(&lbuf[m8*8]);
  }
}

// ---------- gemm2: split-3, 128x64 tile, batched; out = cs @ Hs^T' + bp, K=256 ----------
__global__ __launch_bounds__(256) void gemm2_k(
    const f16* __restrict__ Ah, const f16* __restrict__ Al,
    const f16* __restrict__ Bh, const f16* __restrict__ Bl,
    const float* __restrict__ bias, float* __restrict__ Cf)
{
  __shared__ __align__(16) char lds[49152];   // Ah 16K | Al 16K | Bh 8K | Bl 8K
  const int tid = threadIdx.x;
  const int wid = tid >> 6, lane = tid & 63;
  int flat = (blockIdx.z * 8 + blockIdx.y) * 16 + blockIdx.x;
  int swz = (flat & 7) * 64 + (flat >> 3);    // bijective XCD swizzle, 512 blocks
  const int bx = swz & 15;
  const int t2 = swz >> 4;
  const int by = t2 & 7, z = t2 >> 3;
  const int brow = by * 128;
  const int bcol = bx * 64;
  const int wm = wid >> 1, wn = wid & 1;
  const int asel = lane >> 4, l15 = lane & 15;
  const int K = 256, N = 1024, MZ = 1024;
  const f16* Az_h = Ah + (size_t)z*MZ*K;
  const f16* Az_l = Al + (size_t)z*MZ*K;
  const f16* Bz_h = Bh + (size_t)z*N*K;
  const f16* Bz_l = Bl + (size_t)z*N*K;

  f32x4 acc[4][2];
  #pragma unroll
  for (int i = 0; i < 4; ++i)
    #pragma unroll
    for (int jx = 0; jx < 2; ++jx)
      acc[i][jx] = (f32x4){0.f, 0.f, 0.f, 0.f};

  for (int t = 0; t < 4; ++t) {
    const int k0 = t * 64;
    __syncthreads();
    #pragma unroll
    for (int r = 0; r < 12; ++r) {
      const char* src;
      if (r < 8) {
        int ci = ((r & 3) << 8) + tid;
        int row = ci >> 3, kc = ci & 7;
        int kcg = kc ^ (row & 7);
        const f16* base = (r < 4) ? Az_h : Az_l;
        src = (const char*)(base + (size_t)(brow + row) * K + k0 + kcg * 8);
      } else {
        int ci = ((r & 1) << 8) + tid;
        int col = ci >> 3, kc = ci & 7;
        int kcg = kc ^ (col & 7);
        const f16* base = (r < 10) ? Bz_h : Bz_l;
        src = (const char*)(base + (size_t)(bcol + col) * K + k0 + kcg * 8);
      }
      char* dst = lds + (r * 256 + wid * 64) * 16;
      __builtin_amdgcn_global_load_lds(
          (const __attribute__((address_space(1))) unsigned int*)src,
          (__attribute__((address_space(3))) unsigned int*)dst, 16, 0, 0);
    }
    __syncthreads();
    #pragma unroll
    for (int kk = 0; kk < 2; ++kk) {
      f16x8 afh[4], afl[4], bfh[2], bfl[2];
      #pragma unroll
      for (int mf = 0; mf < 4; ++mf) {
        int row = wm * 64 + mf * 16 + l15;
        int kcx = (kk * 4 + asel) ^ (row & 7);
        int off = row * 128 + kcx * 16;
        afh[mf] = *reinterpret_cast<const f16x8*>(lds + off);
        afl[mf] = *reinterpret_cast<const f16x8*>(lds + 16384 + off);
      }
      #pragma unroll
      for (int nf = 0; nf < 2; ++nf) {
        int col = wn * 32 + nf * 16 + l15;
        int kcx = (kk * 4 + asel) ^ (col & 7);
        int off = col * 128 + kcx * 16;
        bfh[nf] = *reinterpret_cast<const f16x8*>(lds + 32768 + off);
        bfl[nf] = *reinterpret_cast<const f16x8*>(lds + 40960 + off);
      }
      #pragma unroll
      for (int mf = 0; mf < 4; ++mf)
        #pragma unroll
        for (int nf = 0; nf < 2; ++nf) {
          acc[mf][nf] = __builtin_amdgcn_mfma_f32_16x16x32_f16(afh[mf], bfh[nf], acc[mf][nf], 0, 0, 0);
          acc[mf][nf] = __builtin_amdgcn_mfma_f32_16x16x32_f16(afh[mf], bfl[nf], acc[mf][nf], 0, 0, 0);
          acc[mf][nf] = __builtin_amdgcn_mfma_f32_16x16x32_f16(afl[mf], bfh[nf], acc[mf][nf], 0, 0, 0);
        }
    }
  }
  const int crow0 = z*MZ + brow + wm * 64 + asel * 4;
  const int ccol0 = bcol + wn * 32 + l15;
  #pragma unroll
  for (int nf = 0; nf < 2; ++nf) {
    float bv = bias[ccol0 + nf * 16];
    #pragma unroll
    for (int mf = 0; mf < 4; ++mf)
      #pragma unroll
      for (int jx = 0; jx < 4; ++jx)
        Cf[(size_t)(crow0 + mf*16 + jx) * N + ccol0 + nf*16] = acc[mf][nf][jx] + bv;
  }
}

// ---------- row LayerNorm in-place ----------
__global__ __launch_bounds__(256) void ln_kernel(
    float* __restrict__ out, const float* __restrict__ gamma,
    const float* __restrict__ beta)
{
  int row = blockIdx.x, tid = threadIdx.x;
  float4 x = *reinterpret_cast<float4*>(&out[(size_t)row*EMB + tid*4]);
  float sum = x.x + x.y + x.z + x.w;
  float ssq = x.x*x.x + x.y*x.y + x.z*x.z + x.w*x.w;
  #pragma unroll
  for (int off = 32; off > 0; off >>= 1) {
    sum += __shfl_down(sum, off);
    ssq += __shfl_down(ssq, off);
  }
  __shared__ float red[8];
  int wave = tid >> 6, lane = tid & 63;
  if (lane == 0) { red[wave] = sum; red[4+wave] = ssq; }
  __syncthreads();
  if (tid == 0) {
    float a = red[0]+red[1]+red[2]+red[3];
    float qq = red[4]+red[5]+red[6]+red[7];
    float mean = a * (1.f/EMB);
    float var  = qq * (1.f/EMB) - mean*mean;
    red[0] = mean;
    red[1] = 1.0f / sqrtf(var + 1e-6f);
  }
  __syncthreads();
  float mean = red[0], inv = red[1];
  float4 gv = *reinterpret_cast<const float4*>(&gamma[tid*4]);
  float4 bv = *reinterpret_cast<const float4*>(&beta[tid*4]);
  x.x = (x.x - mean)*inv*gv.x + bv.x;
  x.y = (x.y - mean)*inv*gv.y + bv.y;
  x.z = (x.z - mean)*inv*gv.z + bv.z;
  x.w = (x.w - mean)*inv*gv.w + bv.w;
  *reinterpret_cast<float4*>(&out[(size_t)row*EMB + tid*4]) = x;
}

extern "C" void kernel_launch(void* const* d_in, const int* in_sizes, int n_in,
                              void* d_out, int out_size, void* d_ws, size_t ws_size,
                              hipStream_t stream)
{
  const float* k   = (const float*)d_in[0];
  const float* q   = (const float*)d_in[1];
  const float* v   = (const float*)d_in[2];
  const float* Wq  = (const float*)d_in[3];
  const float* bq  = (const float*)d_in[4];
  const float* Wk  = (const float*)d_in[5];
  const float* Wv  = (const float*)d_in[6];
  const float* Wp  = (const float*)d_in[7];
  const float* bp  = (const float*)d_in[8];
  const float* aw  = (const float*)d_in[9];
  const float* gamma = (const float*)d_in[10];
  const float* beta  = (const float*)d_in[11];
  float* out = (float*)d_out;

  float* ws    = (float*)d_ws;
  float* uq    = ws;                    // 16384
  float* uk    = uq + 16384;            // 16384
  float* cq    = uk + 16384;            // 16
  float* sq    = cq + 16;               // 65536
  float* sk    = sq + 65536;            // 65536
  float* nodes = sk + 65536;            // 1024
  float* Wn    = nodes + 1024;          // 1024
  // f32 end: 165,904 floats (663,616 B, 16B-aligned)
  const size_t MEG = 1048576;
  f16* f16b  = (f16*)(ws + 165904);
  f16* WvTh  = f16b;                    // 1M f16
  f16* vTh   = f16b + 1*MEG;            // 4M
  f16* wh    = f16b + 5*MEG;            // 1M (1024x1024)
  f16* Ph    = f16b + 6*MEG;            // 1M (1024x1024)
  f16* csh   = f16b + 7*MEG;            // 1M (4096x256)
  f16* csl   = f16b + 8*MEG;            // 1M
  f16* Hsh   = f16b + 9*MEG;            // 1M (4096x256)
  f16* Hsl   = f16b + 10*MEG;           // 1M  -> end 11M f16 (22MB)

  // 1. fold attention weights
  fold_kernel<<<129, 256, 0, stream>>>(Wq, Wk, bq, aw, uq, uk, cq);
  // 2. sq / sk
  sqsk2_kernel<<<1024, 256, 0, stream>>>(q, k, uq, uk, cq, sq, sk);
  // 3. Chebyshev nodes (MN=16)
  nodes_kernel<<<64, 256, 0, stream>>>(sq, nodes);
  // 4. v + Wv transpose to f16 (one launch)
  ztrans_kernel<<<dim3(16,16,5), 256, 0, stream>>>(v, Wv, vTh, WvTh);
  // 5. w matrix + row sums
  hipMemsetAsync(Wn, 0, 1024*sizeof(float), stream);
  wmat_kernel<<<dim3(4,16,4), 256, 0, stream>>>(sk, nodes, wh, Wn);
  // 6. P = w @ v^T  (plain f16, 64x64 tiles, 256 blocks)
  gemm1_f16<<<dim3(16,16), 256, 0, stream>>>(wh, vTh, Ph);
  // 7. barycentric coefficients (f16 split)
  coeff2_kernel<<<dim3(64,4), 256, 0, stream>>>(sq, nodes, Wn, csh, csl);
  // 8. fused G + Hs
  ghprep_kernel<<<dim3(4,16,4), 256, 0, stream>>>(Ph, WvTh, Wp, Hsh, Hsl);
  // 9. out = cs @ Hs^T' + bp  (split-3, K=256)
  gemm2_k<<<dim3(16,8,4), 256, 0, stream>>>(csh, csl, Hsh, Hsl, bp, out);
  // 10. LayerNorm in-place
  ln_kernel<<<ROWS, 256, 0, stream>>>(out, gamma, beta);
}